// Round 3
// baseline (518.019 us; speedup 1.0000x reference)
//
#include <hip/hip_runtime.h>
#include <hip/hip_cooperative_groups.h>
#include <hip/hip_bf16.h>
#include <math.h>

namespace cg = cooperative_groups;

#define NQ 4096
#define NK 4096
#define QD 256
#define KD 320
#define HID 256
#define NH 8
#define DH 32
#define NB 16
#define LN_EPS 1e-5f
#define ATT_SCALE 0.17677669529663687f   // 1/sqrt(32)

typedef unsigned short ushort_t;
typedef __attribute__((ext_vector_type(8))) short bf16x8_t;
typedef __attribute__((ext_vector_type(4))) short bf16x4_t;
typedef __attribute__((ext_vector_type(4))) float f32x4_t;

// ---------------------------------------------------------------------------
// ws layout (float offsets), ~9 MB. No input staging — phases read d_in
// directly with inline dtype conversion.
// ---------------------------------------------------------------------------
#define OFF_Q2B   0         // bf16 [4096][256]
#define OFF_K2B   524288    // bf16 [4096][256]
#define OFF_V2B   1048576   // bf16 [4096][256]
#define OFF_CTXB  1572864   // bf16 [4096][256]
#define OFF_WQT   2097152   // bf16 WeffQT [256][256]
#define OFF_WKT   2129920   // bf16 WeffKT [256][320]
#define OFF_WVT   2170880   // bf16 WeffVT [256][320]
#define OFF_WOT   2211840   // bf16 WeffOT [256][256]
#define OFF_BEFF  2244608   // f32 [4][256]: Q,K,V,O
#define OFF_KST   2245632   // 16 int
#define OFF_KEN   2245648   // 16 int
#define OFF_FLAG  2245664   // 1 int (fallback path only)

struct KArgs {
    const void* in[18];
    float* ws;
    void* out;
};

__device__ __forceinline__ float bf16_bits_to_f(ushort_t s) {
    unsigned int u = (unsigned int)s << 16;
    float f;
    __builtin_memcpy(&f, &u, 4);
    return f;
}

__device__ __forceinline__ ushort_t f_to_bf16_bits(float v) {
    __hip_bfloat16 t = (__hip_bfloat16)v;
    ushort_t b;
    __builtin_memcpy(&b, &t, 2);
    return b;
}

// dtype-generic loaders: F32=false -> input is bf16; F32=true -> input is f32
template <bool F32>
__device__ __forceinline__ bf16x8_t ld8(const void* p, size_t idx) {
    if constexpr (!F32) {
        return *(const bf16x8_t*)((const ushort_t*)p + idx);
    } else {
        f32x4_t f0 = *(const f32x4_t*)((const float*)p + idx);
        f32x4_t f1 = *(const f32x4_t*)((const float*)p + idx + 4);
        bf16x8_t h;
#pragma unroll
        for (int e = 0; e < 4; ++e) h[e] = (short)f_to_bf16_bits(f0[e]);
#pragma unroll
        for (int e = 0; e < 4; ++e) h[4 + e] = (short)f_to_bf16_bits(f1[e]);
        return h;
    }
}

template <bool F32>
__device__ __forceinline__ float ld1f(const void* p, size_t idx) {
    if constexpr (F32) return ((const float*)p)[idx];
    else               return bf16_bits_to_f(((const ushort_t*)p)[idx]);
}

template <bool F32>
__device__ __forceinline__ ushort_t ld1h(const void* p, size_t idx) {
    if constexpr (F32) return f_to_bf16_bits(((const float*)p)[idx]);
    else               return ((const ushort_t*)p)[idx];
}

// per-block dtype probe on first 8KB of query_nodes (in-bounds either way)
__device__ __forceinline__ int detect_flag(const void* probe_v, int tid) {
    __shared__ float s_red[4];
    const ushort_t* probe = (const ushort_t*)probe_v;
    float mx = 0.f;
    for (int i = tid; i < 4096; i += 256) {
        float f = fabsf(bf16_bits_to_f(probe[i]));
        if (!(f == f)) f = 1e38f;
        mx = fmaxf(mx, f);
    }
    for (int off = 32; off; off >>= 1) mx = fmaxf(mx, __shfl_xor(mx, off, 64));
    if ((tid & 63) == 0) s_red[tid >> 6] = mx;
    __syncthreads();
    float m2 = fmaxf(fmaxf(s_red[0], s_red[1]), fmaxf(s_red[2], s_red[3]));
    __syncthreads();
    return (m2 < 100.f) ? 1 : 0;
}

// ---------------------------------------------------------------------------
// P1 bodies: ranges + weight-fusion GEMMs + biases
// ---------------------------------------------------------------------------
__device__ __forceinline__ void ranges_body(KArgs& a, float* ws, int bid, int tid) {
    const int* kb = (const int*)a.in[17];
    int* kstart = (int*)(ws + OFF_KST);
    int* kend   = (int*)(ws + OFF_KEN);
    int j = bid * 256 + tid;
    if (j < NK) {
        int b = kb[j];
        if (j == 0) {
            for (int x = 0; x < b; ++x) { kstart[x] = 0; kend[x] = 0; }
            kstart[b] = 0;
        } else {
            int bp = kb[j - 1];
            if (bp != b) {
                kend[bp] = j;
                for (int x = bp + 1; x < b; ++x) { kstart[x] = j; kend[x] = j; }
                kstart[b] = j;
            }
        }
        if (j == NK - 1) {
            kend[b] = NK;
            for (int x = b + 1; x < NB; ++x) { kstart[x] = NK; kend[x] = NK; }
        }
    }
}

template <bool F32>
__device__ __forceinline__ void fuse_qkv_tile(const void* A, size_t abase,
                                              const void* B, ushort_t* Out,
                                              int N, int m0, int n0,
                                              int col, int quad) {
    f32x4_t acc[4];
#pragma unroll
    for (int t = 0; t < 4; ++t) acc[t] = (f32x4_t){0.f, 0.f, 0.f, 0.f};
    size_t aoff = abase + (size_t)(m0 + col) * 256 + quad * 8;
    size_t boff = (size_t)(n0 + col) * 256 + quad * 8;
#pragma unroll
    for (int kc = 0; kc < 256; kc += 32) {
        bf16x8_t af = ld8<F32>(A, aoff + kc);
#pragma unroll
        for (int t = 0; t < 4; ++t) {
            bf16x8_t bf = ld8<F32>(B, boff + (size_t)t * 16 * 256 + kc);
            acc[t] = __builtin_amdgcn_mfma_f32_16x16x32_bf16(af, bf, acc[t], 0, 0, 0);
        }
    }
#pragma unroll
    for (int t = 0; t < 4; ++t)
#pragma unroll
        for (int rr = 0; rr < 4; ++rr)
            Out[(size_t)(m0 + quad * 4 + rr) * N + n0 + t * 16 + col] =
                f_to_bf16_bits(acc[t][rr]);
}

// WeffOT[n][k'] = sum_j Wo[j][n] * mow[k'][j]  (A-frag gathered from Wo cols)
template <bool F32>
__device__ __forceinline__ void fuse_o_tile(const void* Wo, const void* Mow,
                                            ushort_t* Out, int m0, int n0,
                                            int col, int quad) {
    f32x4_t acc[4];
#pragma unroll
    for (int t = 0; t < 4; ++t) acc[t] = (f32x4_t){0.f, 0.f, 0.f, 0.f};
#pragma unroll
    for (int kc = 0; kc < 256; kc += 32) {
        bf16x8_t af;
#pragma unroll
        for (int t = 0; t < 8; ++t)
            af[t] = (short)ld1h<F32>(Wo, (size_t)(kc + quad * 8 + t) * 256 + m0 + col);
#pragma unroll
        for (int t = 0; t < 4; ++t) {
            bf16x8_t bf = ld8<F32>(Mow, (size_t)(n0 + t * 16 + col) * 256 + quad * 8 + kc);
            acc[t] = __builtin_amdgcn_mfma_f32_16x16x32_bf16(af, bf, acc[t], 0, 0, 0);
        }
    }
#pragma unroll
    for (int t = 0; t < 4; ++t)
#pragma unroll
        for (int rr = 0; rr < 4; ++rr)
            Out[(size_t)(m0 + quad * 4 + rr) * 256 + n0 + t * 16 + col] =
                f_to_bf16_bits(acc[t][rr]);
}

template <bool F32>
__device__ __forceinline__ void fuse_dispatch(KArgs& a, float* ws, int r,
                                              int wv, int col, int quad, int fl) {
    const void* A; const void* B; ushort_t* Out;
    size_t abase; int N, mb, nb, typ;
    if (r < 16)      { typ = 0; A = a.in[8]; abase = 0;      B = a.in[2]; Out = (ushort_t*)(ws + OFF_WQT); N = 256; mb = r >> 2; nb = r & 3; }
    else if (r < 36) { typ = 0; int rr = r - 16; A = a.in[8]; abase = 65536;  B = a.in[4]; Out = (ushort_t*)(ws + OFF_WKT); N = 320; mb = rr / 5; nb = rr % 5; }
    else if (r < 56) { typ = 0; int rr = r - 36; A = a.in[8]; abase = 131072; B = a.in[6]; Out = (ushort_t*)(ws + OFF_WVT); N = 320; mb = rr / 5; nb = rr % 5; }
    else             { typ = 1; int rr = r - 56; A = a.in[12]; abase = 0; B = a.in[10]; Out = (ushort_t*)(ws + OFF_WOT); N = 256; mb = rr >> 2; nb = rr & 3; }
    int m0 = mb * 64 + wv * 16, n0 = nb * 64;
    if (typ == 0) fuse_qkv_tile<F32>(A, abase, B, Out, N, m0, n0, col, quad);
    else          fuse_o_tile<F32>(A, B, Out, m0, n0, col, quad);
    (void)fl;
}

template <bool F32>
__device__ __forceinline__ void bias_body(KArgs& a, float* ws, int m, int tid) {
    __shared__ float bsh[256];
    float* beff = ws + OFF_BEFF;
    if (m < 3) {
        const void* bsrc = (m == 0) ? a.in[3] : (m == 1) ? a.in[5] : a.in[7];
        bsh[tid] = ld1f<F32>(bsrc, tid);
        __syncthreads();
        float acc = 0.f;
        size_t row = (size_t)(m * 256 + tid) * 256;
#pragma unroll 4
        for (int kc = 0; kc < 256; kc += 8) {
            bf16x8_t wr = ld8<F32>(a.in[8], row + kc);
#pragma unroll
            for (int t = 0; t < 8; ++t)
                acc += bsh[kc + t] * bf16_bits_to_f((ushort_t)wr[t]);
        }
        acc += ld1f<F32>(a.in[9], m * 256 + tid);
        beff[m * 256 + tid] = acc;
    } else {
        bsh[tid] = ld1f<F32>(a.in[11], tid);   // mha_ob
        __syncthreads();
        float acc = 0.f;
        for (int k = 0; k < 256; ++k)
            acc += bsh[k] * ld1f<F32>(a.in[12], (size_t)k * 256 + tid);  // Wo[k][j]
        acc += ld1f<F32>(a.in[13], tid);
        beff[3 * 256 + tid] = acc;
    }
}

// P1 block-role dispatcher (shared by mega and fallback k_fuse)
template <bool MEGA>
__device__ __forceinline__ void p1_body(KArgs& a, float* ws, int bid, int tid,
                                        int wv, int col, int quad, int fl) {
    if (bid < 16) {
        ranges_body(a, ws, bid, tid);
    } else if (bid < 88) {
        int r = bid - 16;
        if (fl) fuse_dispatch<false>(a, ws, r, wv, col, quad, fl);
        else    fuse_dispatch<true >(a, ws, r, wv, col, quad, fl);
    } else if (bid < 92) {
        int m = bid - 88;
        if (fl) bias_body<false>(a, ws, m, tid);
        else    bias_body<true >(a, ws, m, tid);
    }
}

// ---------------------------------------------------------------------------
// P2 body: QKV projection unit (64x64 tile per unit, 4 waves)
// ---------------------------------------------------------------------------
template <bool F32, int KK>
__device__ __forceinline__ void proj_body(const void* X, const ushort_t* WT,
                                          const float* bias, ushort_t* Z,
                                          int m0, int n0, int col, int quad) {
    f32x4_t acc[4];
#pragma unroll
    for (int t = 0; t < 4; ++t) acc[t] = (f32x4_t){0.f, 0.f, 0.f, 0.f};
    size_t aoff = (size_t)(m0 + col) * KK + quad * 8;
    const ushort_t* Wrow = WT + (size_t)(n0 + col) * KK + quad * 8;
#pragma unroll
    for (int kc = 0; kc < KK; kc += 32) {
        bf16x8_t af = ld8<F32>(X, aoff + kc);
#pragma unroll
        for (int t = 0; t < 4; ++t) {
            bf16x8_t bf = *(const bf16x8_t*)(Wrow + (size_t)t * 16 * KK + kc);
            acc[t] = __builtin_amdgcn_mfma_f32_16x16x32_bf16(af, bf, acc[t], 0, 0, 0);
        }
    }
#pragma unroll
    for (int t = 0; t < 4; ++t)
#pragma unroll
        for (int rr = 0; rr < 4; ++rr) {
            int n = n0 + t * 16 + col;
            Z[(size_t)(m0 + quad * 4 + rr) * 256 + n] =
                f_to_bf16_bits(acc[t][rr] + bias[n]);
        }
}

template <bool F32>
__device__ __forceinline__ void qkv_unit(KArgs& a, float* ws, int u,
                                         int wv, int col, int quad) {
    const float* beff = ws + OFF_BEFF;
    if (u < 256) {
        int m0 = (u >> 2) * 64 + wv * 16, n0 = (u & 3) * 64;
        const ushort_t* WT = (const ushort_t*)(ws + OFF_WQT);
        ushort_t* Z = (ushort_t*)(ws + OFF_Q2B);
        proj_body<F32, 256>(a.in[0], WT, beff, Z, m0, n0, col, quad);
    } else if (u < 512) {
        int uu = u - 256;
        int m0 = (uu >> 2) * 64 + wv * 16, n0 = (uu & 3) * 64;
        const ushort_t* WT = (const ushort_t*)(ws + OFF_WKT);
        ushort_t* Z = (ushort_t*)(ws + OFF_K2B);
        proj_body<F32, 320>(a.in[1], WT, beff + 256, Z, m0, n0, col, quad);
    } else {
        int uu = u - 512;
        int m0 = (uu >> 2) * 64 + wv * 16, n0 = (uu & 3) * 64;
        const ushort_t* WT = (const ushort_t*)(ws + OFF_WVT);
        ushort_t* Z = (ushort_t*)(ws + OFF_V2B);
        proj_body<F32, 320>(a.in[1], WT, beff + 512, Z, m0, n0, col, quad);
    }
}

// ---------------------------------------------------------------------------
// P3 body: flash attention unit (one 16-query tile x 4 heads per block)
// ---------------------------------------------------------------------------
__device__ __forceinline__ void attn_body(KArgs& a, float* ws, int bid,
                                          int wv, int lane) {
    const ushort_t* q2b = (const ushort_t*)(ws + OFF_Q2B);
    const ushort_t* k2b = (const ushort_t*)(ws + OFF_K2B);
    const ushort_t* v2b = (const ushort_t*)(ws + OFF_V2B);
    const int* qb  = (const int*)a.in[16];
    const int* kst = (const int*)(ws + OFF_KST);
    const int* ken = (const int*)(ws + OFF_KEN);
    ushort_t* ctxb = (ushort_t*)(ws + OFF_CTXB);

    int qt = bid >> 1;
    int h  = ((bid & 1) << 2) | wv;
    int q0 = qt * 16;
    int col  = lane & 15;
    int quad = lane >> 4;

    int qq = q0 + col;
    int bq_ = qb[qq];
    int j0q = kst[bq_], j1q = ken[bq_];
    int jlo = j0q, jhi = j1q;
#pragma unroll
    for (int off = 1; off < 16; off <<= 1) {
        jlo = min(jlo, __shfl_xor(jlo, off, 64));
        jhi = max(jhi, __shfl_xor(jhi, off, 64));
    }

    bf16x8_t qf = *(const bf16x8_t*)(q2b + (size_t)qq * HID + h * DH + quad * 8);

    f32x4_t accO = {0.f, 0.f, 0.f, 0.f};
    float l_st = 0.f;   // per-lane partial: sum over this lane's keys, query=col

    for (int kt = jlo; kt < jhi; kt += 16) {
        int krow = kt + col;
        if (krow > NK - 1) krow = NK - 1;
        bf16x8_t kf = *(const bf16x8_t*)(k2b + (size_t)krow * HID + h * DH + quad * 8);
        ushort_t vr[4];
#pragma unroll
        for (int j = 0; j < 4; ++j) {
            int vrow = kt + quad * 4 + j;
            if (vrow > NK - 1) vrow = NK - 1;
            vr[j] = v2b[(size_t)vrow * HID + h * DH + col];
        }
        // S tile: row (quad*4+r) = key, col (lane&15) = query
        f32x4_t S = __builtin_amdgcn_mfma_f32_16x16x32_bf16(
            kf, qf, (f32x4_t){0.f, 0.f, 0.f, 0.f}, 0, 0, 0);

        bf16x4_t pb, vb;
#pragma unroll
        for (int r = 0; r < 4; ++r) {
            int kk = kt + quad * 4 + r;
            bool ok = (kk >= j0q) && (kk < j1q);
            float p = ok ? __expf(S[r] * ATT_SCALE) : 0.f;
            l_st += p;
            pb[r] = (short)f_to_bf16_bits(p);
            vb[r] = (short)vr[r];
        }
        accO = __builtin_amdgcn_mfma_f32_16x16x16bf16_1k(pb, vb, accO, 0, 0, 0);
    }

    // total l per query=col: reduce across the 4 quads
    l_st += __shfl_xor(l_st, 16, 64);
    l_st += __shfl_xor(l_st, 32, 64);

#pragma unroll
    for (int r = 0; r < 4; ++r) {
        int qrow_local = quad * 4 + r;               // accO row = query index
        float lq = __shfl(l_st, qrow_local, 64);     // lane qrow_local has col==qrow_local
        float o = (lq > 0.f) ? accO[r] / lq : 0.f;
        int qrow = q0 + qrow_local;
        ctxb[(size_t)qrow * HID + h * DH + col] = f_to_bf16_bits(o);
    }
}

// ---------------------------------------------------------------------------
// P4 body: O-projection + residual + LayerNorm fused (64 units)
// ---------------------------------------------------------------------------
template <bool F32>
__device__ __forceinline__ void oln_body(KArgs& a, float* ws, int u,
                                         int wv, int col, int quad, int fl) {
    const ushort_t* ctxb = (const ushort_t*)(ws + OFF_CTXB);
    const ushort_t* wot  = (const ushort_t*)(ws + OFF_WOT);
    const float* beffO = ws + OFF_BEFF + 3 * 256;

    int m0 = u * 64 + wv * 16;
    f32x4_t acc[16];
#pragma unroll
    for (int t = 0; t < 16; ++t) acc[t] = (f32x4_t){0.f, 0.f, 0.f, 0.f};
    const ushort_t* Xrow = ctxb + (size_t)(m0 + col) * 256 + quad * 8;
    const ushort_t* Wbase = wot + (size_t)col * 256 + quad * 8;
#pragma unroll
    for (int kc = 0; kc < 256; kc += 32) {
        bf16x8_t af = *(const bf16x8_t*)(Xrow + kc);
#pragma unroll
        for (int t = 0; t < 16; ++t) {
            bf16x8_t bf = *(const bf16x8_t*)(Wbase + (size_t)t * 16 * 256 + kc);
            acc[t] = __builtin_amdgcn_mfma_f32_16x16x32_bf16(af, bf, acc[t], 0, 0, 0);
        }
    }
    float s_[4] = {0.f, 0.f, 0.f, 0.f};
    float ss_[4] = {0.f, 0.f, 0.f, 0.f};
#pragma unroll
    for (int t = 0; t < 16; ++t) {
        int n = t * 16 + col;
        float b = beffO[n];
#pragma unroll
        for (int rr = 0; rr < 4; ++rr) {
            int m = m0 + quad * 4 + rr;
            float x = acc[t][rr] + b + ld1f<F32>(a.in[0], (size_t)m * 256 + n);
            acc[t][rr] = x;
            s_[rr] += x;
            ss_[rr] += x * x;
        }
    }
#pragma unroll
    for (int off = 1; off < 16; off <<= 1) {
#pragma unroll
        for (int rr = 0; rr < 4; ++rr) {
            s_[rr]  += __shfl_xor(s_[rr],  off, 16);
            ss_[rr] += __shfl_xor(ss_[rr], off, 16);
        }
    }
    float mu[4], inv[4];
#pragma unroll
    for (int rr = 0; rr < 4; ++rr) {
        mu[rr] = s_[rr] * (1.f / QD);
        float var = ss_[rr] * (1.f / QD) - mu[rr] * mu[rr];
        inv[rr] = rsqrtf(var + LN_EPS);
    }
#pragma unroll
    for (int t = 0; t < 16; ++t) {
        int n = t * 16 + col;
        float g = ld1f<F32>(a.in[14], n), bb = ld1f<F32>(a.in[15], n);
#pragma unroll
        for (int rr = 0; rr < 4; ++rr) {
            int m = m0 + quad * 4 + rr;
            float y = (acc[t][rr] - mu[rr]) * inv[rr] * g + bb;
            size_t idx = (size_t)m * 256 + n;
            if (fl) ((ushort_t*)a.out)[idx] = f_to_bf16_bits(y);
            else    ((float*)a.out)[idx] = y;
        }
    }
}

// ---------------------------------------------------------------------------
// Mega-kernel: one cooperative launch, 4 phases, 3 grid syncs.
// Grid = 512 blocks x 256 threads = exactly 2 blocks/CU (co-residency safe).
// ---------------------------------------------------------------------------
__global__ __launch_bounds__(256, 2) void k_mega(KArgs a) {
    cg::grid_group grid = cg::this_grid();
    float* ws = a.ws;
    const int tid = threadIdx.x, bid = blockIdx.x;
    const int lane = tid & 63, wv = tid >> 6;
    const int col = lane & 15, quad = lane >> 4;
    const int fl = detect_flag(a.in[0], tid);   // per-block, kept in register

    // ---------------- P1: ranges + weight fusion + biases -----------------
    p1_body<true>(a, ws, bid, tid, wv, col, quad, fl);

    __threadfence();
    grid.sync();

    // ---------------- P2: QKV projections (768 units over 512 blocks) -----
    for (int u = bid; u < 768; u += 512) {
        if (fl) qkv_unit<false>(a, ws, u, wv, col, quad);
        else    qkv_unit<true >(a, ws, u, wv, col, quad);
    }

    __threadfence();
    grid.sync();

    // ---------------- P3: flash attention (512 units, 1:1) ----------------
    attn_body(a, ws, bid, wv, lane);

    __threadfence();
    grid.sync();

    // ---------------- P4: O-projection + residual + LayerNorm -------------
    if (bid < 64) {
        if (fl) oln_body<false>(a, ws, bid, wv, col, quad, fl);
        else    oln_body<true >(a, ws, bid, wv, col, quad, fl);
    }
}

// ---------------------------------------------------------------------------
// Fallback path: the 4-kernel pipeline (round-0 baseline, 162 µs known-good),
// used only if hipLaunchCooperativeKernel is rejected by the runtime/capture.
// ---------------------------------------------------------------------------
__global__ __launch_bounds__(256) void k_fuse(KArgs a) {
    float* ws = a.ws;
    const int tid = threadIdx.x, bid = blockIdx.x;
    const int lane = tid & 63, wv = tid >> 6;
    const int col = lane & 15, quad = lane >> 4;
    int fl = detect_flag(a.in[0], tid);
    if (bid == 0 && tid == 0) *(int*)(ws + OFF_FLAG) = fl;
    p1_body<false>(a, ws, bid, tid, wv, col, quad, fl);
}

__global__ __launch_bounds__(256) void k_qkv(KArgs a) {
    float* ws = a.ws;
    const int tid = threadIdx.x, u = blockIdx.x;
    const int lane = tid & 63, wv = tid >> 6;
    const int col = lane & 15, quad = lane >> 4;
    const int fl = *(const int*)(ws + OFF_FLAG);
    if (fl) qkv_unit<false>(a, ws, u, wv, col, quad);
    else    qkv_unit<true >(a, ws, u, wv, col, quad);
}

__global__ __launch_bounds__(256) void k_attn(KArgs a) {
    attn_body(a, a.ws, blockIdx.x, threadIdx.x >> 6, threadIdx.x & 63);
}

__global__ __launch_bounds__(256) void k_oln(KArgs a) {
    float* ws = a.ws;
    const int tid = threadIdx.x;
    const int lane = tid & 63, wv = tid >> 6;
    const int col = lane & 15, quad = lane >> 4;
    const int fl = *(const int*)(ws + OFF_FLAG);
    if (fl) oln_body<false>(a, ws, blockIdx.x, wv, col, quad, fl);
    else    oln_body<true >(a, ws, blockIdx.x, wv, col, quad, fl);
}

extern "C" void kernel_launch(void* const* d_in, const int* in_sizes, int n_in,
                              void* d_out, int out_size, void* d_ws, size_t ws_size,
                              hipStream_t stream) {
    KArgs a;
    for (int i = 0; i < 18; ++i) a.in[i] = d_in[i];
    a.ws = (float*)d_ws;
    a.out = d_out;

    void* params[] = { (void*)&a };
    hipError_t err = hipLaunchCooperativeKernel((const void*)k_mega, dim3(512),
                                                dim3(256), params, 0, stream);
    if (err != hipSuccess) {
        // cooperative launch unavailable — fall back to the 4-kernel pipeline
        k_fuse<<<92, 256, 0, stream>>>(a);
        k_qkv<<<768, 256, 0, stream>>>(a);
        k_attn<<<512, 256, 0, stream>>>(a);
        k_oln<<<64, 256, 0, stream>>>(a);
    }
}

// Round 4
// 148.271 us; speedup vs baseline: 3.4937x; 3.4937x over previous
//
#include <hip/hip_runtime.h>
#include <hip/hip_bf16.h>
#include <math.h>

#define NQ 4096
#define NK 4096
#define QD 256
#define KD 320
#define HID 256
#define NH 8
#define DH 32
#define NB 16
#define LN_EPS 1e-5f
#define ATT_SCALE 0.17677669529663687f   // 1/sqrt(32)

typedef unsigned short ushort_t;
typedef __attribute__((ext_vector_type(8))) short bf16x8_t;
typedef __attribute__((ext_vector_type(4))) short bf16x4_t;
typedef __attribute__((ext_vector_type(4))) float f32x4_t;

// ---------------------------------------------------------------------------
// ws layout (float offsets), ~9 MB. No input staging — kernels read d_in
// directly with inline dtype conversion.
// ---------------------------------------------------------------------------
#define OFF_Q2B   0         // bf16 [4096][256]
#define OFF_K2B   524288    // bf16 [4096][256]
#define OFF_V2B   1048576   // bf16 [4096][256]
#define OFF_CTXB  1572864   // bf16 [4096][256]
#define OFF_WQT   2097152   // bf16 WeffQT [256][256]
#define OFF_WKT   2129920   // bf16 WeffKT [256][320]
#define OFF_WVT   2170880   // bf16 WeffVT [256][320]
#define OFF_WOT   2211840   // bf16 WeffOT [256][256]
#define OFF_BEFF  2244608   // f32 [4][256]: Q,K,V,O
#define OFF_KST   2245632   // 16 int
#define OFF_KEN   2245648   // 16 int
#define OFF_FLAG  2245664   // 1 int

struct KArgs {
    const void* in[18];
    float* ws;
    void* out;
};

__device__ __forceinline__ float bf16_bits_to_f(ushort_t s) {
    unsigned int u = (unsigned int)s << 16;
    float f;
    __builtin_memcpy(&f, &u, 4);
    return f;
}

__device__ __forceinline__ ushort_t f_to_bf16_bits(float v) {
    __hip_bfloat16 t = (__hip_bfloat16)v;
    ushort_t b;
    __builtin_memcpy(&b, &t, 2);
    return b;
}

// dtype-generic loaders: F32=false -> input is bf16; F32=true -> input is f32
template <bool F32>
__device__ __forceinline__ bf16x8_t ld8(const void* p, size_t idx) {
    if constexpr (!F32) {
        return *(const bf16x8_t*)((const ushort_t*)p + idx);
    } else {
        f32x4_t f0 = *(const f32x4_t*)((const float*)p + idx);
        f32x4_t f1 = *(const f32x4_t*)((const float*)p + idx + 4);
        bf16x8_t h;
#pragma unroll
        for (int e = 0; e < 4; ++e) h[e] = (short)f_to_bf16_bits(f0[e]);
#pragma unroll
        for (int e = 0; e < 4; ++e) h[4 + e] = (short)f_to_bf16_bits(f1[e]);
        return h;
    }
}

template <bool F32>
__device__ __forceinline__ float ld1f(const void* p, size_t idx) {
    if constexpr (F32) return ((const float*)p)[idx];
    else               return bf16_bits_to_f(((const ushort_t*)p)[idx]);
}

template <bool F32>
__device__ __forceinline__ ushort_t ld1h(const void* p, size_t idx) {
    if constexpr (F32) return f_to_bf16_bits(((const float*)p)[idx]);
    else               return ((const ushort_t*)p)[idx];
}

// per-block dtype probe on first 8KB of query_nodes (in-bounds either way)
__device__ __forceinline__ int detect_flag(const void* probe_v, int tid) {
    __shared__ float s_red[4];
    const ushort_t* probe = (const ushort_t*)probe_v;
    float mx = 0.f;
    for (int i = tid; i < 4096; i += 256) {
        float f = fabsf(bf16_bits_to_f(probe[i]));
        if (!(f == f)) f = 1e38f;
        mx = fmaxf(mx, f);
    }
    for (int off = 32; off; off >>= 1) mx = fmaxf(mx, __shfl_xor(mx, off, 64));
    if ((tid & 63) == 0) s_red[tid >> 6] = mx;
    __syncthreads();
    float m2 = fmaxf(fmaxf(s_red[0], s_red[1]), fmaxf(s_red[2], s_red[3]));
    __syncthreads();
    return (m2 < 100.f) ? 1 : 0;
}

// ---------------------------------------------------------------------------
// K1: ranges (blocks 0..15) + weight-fusion GEMMs (16..87) + biases (88..91)
// ---------------------------------------------------------------------------
template <bool F32>
__device__ __forceinline__ void fuse_qkv_tile(const void* A, size_t abase,
                                              const void* B, ushort_t* Out,
                                              int N, int m0, int n0,
                                              int col, int quad) {
    f32x4_t acc[4];
#pragma unroll
    for (int t = 0; t < 4; ++t) acc[t] = (f32x4_t){0.f, 0.f, 0.f, 0.f};
    size_t aoff = abase + (size_t)(m0 + col) * 256 + quad * 8;
    size_t boff = (size_t)(n0 + col) * 256 + quad * 8;
#pragma unroll
    for (int kc = 0; kc < 256; kc += 32) {
        bf16x8_t af = ld8<F32>(A, aoff + kc);
#pragma unroll
        for (int t = 0; t < 4; ++t) {
            bf16x8_t bf = ld8<F32>(B, boff + (size_t)t * 16 * 256 + kc);
            acc[t] = __builtin_amdgcn_mfma_f32_16x16x32_bf16(af, bf, acc[t], 0, 0, 0);
        }
    }
#pragma unroll
    for (int t = 0; t < 4; ++t)
#pragma unroll
        for (int rr = 0; rr < 4; ++rr)
            Out[(size_t)(m0 + quad * 4 + rr) * N + n0 + t * 16 + col] =
                f_to_bf16_bits(acc[t][rr]);
}

// WeffOT[n][k'] = sum_j Wo[j][n] * mow[k'][j]  (A-frag gathered from Wo cols)
template <bool F32>
__device__ __forceinline__ void fuse_o_tile(const void* Wo, const void* Mow,
                                            ushort_t* Out, int m0, int n0,
                                            int col, int quad) {
    f32x4_t acc[4];
#pragma unroll
    for (int t = 0; t < 4; ++t) acc[t] = (f32x4_t){0.f, 0.f, 0.f, 0.f};
#pragma unroll
    for (int kc = 0; kc < 256; kc += 32) {
        bf16x8_t af;
#pragma unroll
        for (int t = 0; t < 8; ++t)
            af[t] = (short)ld1h<F32>(Wo, (size_t)(kc + quad * 8 + t) * 256 + m0 + col);
#pragma unroll
        for (int t = 0; t < 4; ++t) {
            bf16x8_t bf = ld8<F32>(Mow, (size_t)(n0 + t * 16 + col) * 256 + quad * 8 + kc);
            acc[t] = __builtin_amdgcn_mfma_f32_16x16x32_bf16(af, bf, acc[t], 0, 0, 0);
        }
    }
#pragma unroll
    for (int t = 0; t < 4; ++t)
#pragma unroll
        for (int rr = 0; rr < 4; ++rr)
            Out[(size_t)(m0 + quad * 4 + rr) * 256 + n0 + t * 16 + col] =
                f_to_bf16_bits(acc[t][rr]);
}

template <bool F32>
__device__ __forceinline__ void bias_body(KArgs& a, float* ws, int m, int tid) {
    __shared__ float bsh[256];
    float* beff = ws + OFF_BEFF;
    if (m < 3) {
        const void* bsrc = (m == 0) ? a.in[3] : (m == 1) ? a.in[5] : a.in[7];
        bsh[tid] = ld1f<F32>(bsrc, tid);
        __syncthreads();
        float acc = 0.f;
        size_t row = (size_t)(m * 256 + tid) * 256;
#pragma unroll 4
        for (int kc = 0; kc < 256; kc += 8) {
            bf16x8_t wr = ld8<F32>(a.in[8], row + kc);
#pragma unroll
            for (int t = 0; t < 8; ++t)
                acc += bsh[kc + t] * bf16_bits_to_f((ushort_t)wr[t]);
        }
        acc += ld1f<F32>(a.in[9], m * 256 + tid);
        beff[m * 256 + tid] = acc;
    } else {
        bsh[tid] = ld1f<F32>(a.in[11], tid);   // mha_ob
        __syncthreads();
        float acc = 0.f;
        for (int k = 0; k < 256; ++k)
            acc += bsh[k] * ld1f<F32>(a.in[12], (size_t)k * 256 + tid);  // Wo[k][j]
        acc += ld1f<F32>(a.in[13], tid);
        beff[3 * 256 + tid] = acc;
    }
}

__global__ __launch_bounds__(256) void k_fuse(KArgs a) {
    float* ws = a.ws;
    const int tid = threadIdx.x, bid = blockIdx.x;
    const int lane = tid & 63, wv = tid >> 6;
    const int col = lane & 15, quad = lane >> 4;
    int fl = detect_flag(a.in[0], tid);
    if (bid == 0 && tid == 0) *(int*)(ws + OFF_FLAG) = fl;

    if (bid < 16) {
        // batch ranges from sorted key_batch_idx (boundary detection)
        const int* kb = (const int*)a.in[17];
        int* kstart = (int*)(ws + OFF_KST);
        int* kend   = (int*)(ws + OFF_KEN);
        int j = bid * 256 + tid;
        if (j < NK) {
            int b = kb[j];
            if (j == 0) {
                for (int x = 0; x < b; ++x) { kstart[x] = 0; kend[x] = 0; }
                kstart[b] = 0;
            } else {
                int bp = kb[j - 1];
                if (bp != b) {
                    kend[bp] = j;
                    for (int x = bp + 1; x < b; ++x) { kstart[x] = j; kend[x] = j; }
                    kstart[b] = j;
                }
            }
            if (j == NK - 1) {
                kend[b] = NK;
                for (int x = b + 1; x < NB; ++x) { kstart[x] = NK; kend[x] = NK; }
            }
        }
    } else if (bid < 88) {
        int r = bid - 16;
        const void* A; const void* B; ushort_t* Out;
        size_t abase; int N, mb, nb, typ;
        if (r < 16)      { typ = 0; A = a.in[8]; abase = 0;      B = a.in[2]; Out = (ushort_t*)(ws + OFF_WQT); N = 256; mb = r >> 2; nb = r & 3; }
        else if (r < 36) { typ = 0; int rr = r - 16; A = a.in[8]; abase = 65536;  B = a.in[4]; Out = (ushort_t*)(ws + OFF_WKT); N = 320; mb = rr / 5; nb = rr % 5; }
        else if (r < 56) { typ = 0; int rr = r - 36; A = a.in[8]; abase = 131072; B = a.in[6]; Out = (ushort_t*)(ws + OFF_WVT); N = 320; mb = rr / 5; nb = rr % 5; }
        else             { typ = 1; int rr = r - 56; A = a.in[12]; abase = 0; B = a.in[10]; Out = (ushort_t*)(ws + OFF_WOT); N = 256; mb = rr >> 2; nb = rr & 3; }
        int m0 = mb * 64 + wv * 16, n0 = nb * 64;
        if (typ == 0) {
            if (fl) fuse_qkv_tile<false>(A, abase, B, Out, N, m0, n0, col, quad);
            else    fuse_qkv_tile<true >(A, abase, B, Out, N, m0, n0, col, quad);
        } else {
            if (fl) fuse_o_tile<false>(A, B, Out, m0, n0, col, quad);
            else    fuse_o_tile<true >(A, B, Out, m0, n0, col, quad);
        }
    } else {
        int m = bid - 88;
        if (fl) bias_body<false>(a, ws, m, tid);
        else    bias_body<true >(a, ws, m, tid);
    }
}

// ---------------------------------------------------------------------------
// K2: Q/K/V projections, 768 blocks x 4 waves (12 waves/CU; each block reads
// a 64-row weight quarter, not the whole matrix).
// ---------------------------------------------------------------------------
template <bool F32, int KK>
__device__ __forceinline__ void proj_body(const void* X, const ushort_t* WT,
                                          const float* bias, ushort_t* Z,
                                          int m0, int n0, int col, int quad) {
    f32x4_t acc[4];
#pragma unroll
    for (int t = 0; t < 4; ++t) acc[t] = (f32x4_t){0.f, 0.f, 0.f, 0.f};
    size_t aoff = (size_t)(m0 + col) * KK + quad * 8;
    const ushort_t* Wrow = WT + (size_t)(n0 + col) * KK + quad * 8;
#pragma unroll
    for (int kc = 0; kc < KK; kc += 32) {
        bf16x8_t af = ld8<F32>(X, aoff + kc);
#pragma unroll
        for (int t = 0; t < 4; ++t) {
            bf16x8_t bf = *(const bf16x8_t*)(Wrow + (size_t)t * 16 * KK + kc);
            acc[t] = __builtin_amdgcn_mfma_f32_16x16x32_bf16(af, bf, acc[t], 0, 0, 0);
        }
    }
#pragma unroll
    for (int t = 0; t < 4; ++t)
#pragma unroll
        for (int rr = 0; rr < 4; ++rr) {
            int n = n0 + t * 16 + col;
            Z[(size_t)(m0 + quad * 4 + rr) * 256 + n] =
                f_to_bf16_bits(acc[t][rr] + bias[n]);
        }
}

__global__ __launch_bounds__(256) void k_qkv(KArgs a) {
    float* ws = a.ws;
    const int tid = threadIdx.x, u = blockIdx.x;
    const int lane = tid & 63, wv = tid >> 6;
    const int col = lane & 15, quad = lane >> 4;
    const int fl = *(const int*)(ws + OFF_FLAG);
    const float* beff = ws + OFF_BEFF;

    if (u < 256) {
        int m0 = (u >> 2) * 64 + wv * 16, n0 = (u & 3) * 64;
        const ushort_t* WT = (const ushort_t*)(ws + OFF_WQT);
        ushort_t* Z = (ushort_t*)(ws + OFF_Q2B);
        if (fl) proj_body<false, 256>(a.in[0], WT, beff, Z, m0, n0, col, quad);
        else    proj_body<true , 256>(a.in[0], WT, beff, Z, m0, n0, col, quad);
    } else if (u < 512) {
        int uu = u - 256;
        int m0 = (uu >> 2) * 64 + wv * 16, n0 = (uu & 3) * 64;
        const ushort_t* WT = (const ushort_t*)(ws + OFF_WKT);
        ushort_t* Z = (ushort_t*)(ws + OFF_K2B);
        if (fl) proj_body<false, 320>(a.in[1], WT, beff + 256, Z, m0, n0, col, quad);
        else    proj_body<true , 320>(a.in[1], WT, beff + 256, Z, m0, n0, col, quad);
    } else {
        int uu = u - 512;
        int m0 = (uu >> 2) * 64 + wv * 16, n0 = (uu & 3) * 64;
        const ushort_t* WT = (const ushort_t*)(ws + OFF_WVT);
        ushort_t* Z = (ushort_t*)(ws + OFF_V2B);
        if (fl) proj_body<false, 320>(a.in[1], WT, beff + 512, Z, m0, n0, col, quad);
        else    proj_body<true , 320>(a.in[1], WT, beff + 512, Z, m0, n0, col, quad);
    }
}

// ---------------------------------------------------------------------------
// K3: MFMA flash attention, fixed-shift softmax. Two K-tiles per iteration
// with independent accumulators (accO/accO2) to double memory-level
// parallelism and break the serial MFMA dependence chain.
// ---------------------------------------------------------------------------
__global__ __launch_bounds__(256) void k_attn(KArgs a) {
    float* ws = a.ws;
    const ushort_t* q2b = (const ushort_t*)(ws + OFF_Q2B);
    const ushort_t* k2b = (const ushort_t*)(ws + OFF_K2B);
    const ushort_t* v2b = (const ushort_t*)(ws + OFF_V2B);
    const int* qb  = (const int*)a.in[16];
    const int* kst = (const int*)(ws + OFF_KST);
    const int* ken = (const int*)(ws + OFF_KEN);
    ushort_t* ctxb = (ushort_t*)(ws + OFF_CTXB);

    int wave = threadIdx.x >> 6;
    int lane = threadIdx.x & 63;
    int qt = blockIdx.x >> 1;
    int h  = ((blockIdx.x & 1) << 2) | wave;
    int q0 = qt * 16;
    int col  = lane & 15;
    int quad = lane >> 4;

    int qq = q0 + col;
    int bq_ = qb[qq];
    int j0q = kst[bq_], j1q = ken[bq_];
    int jlo = j0q, jhi = j1q;
#pragma unroll
    for (int off = 1; off < 16; off <<= 1) {
        jlo = min(jlo, __shfl_xor(jlo, off, 64));
        jhi = max(jhi, __shfl_xor(jhi, off, 64));
    }

    bf16x8_t qf = *(const bf16x8_t*)(q2b + (size_t)qq * HID + h * DH + quad * 8);

    f32x4_t accO  = {0.f, 0.f, 0.f, 0.f};
    f32x4_t accO2 = {0.f, 0.f, 0.f, 0.f};
    float l_st = 0.f;   // per-lane partial: sum over this lane's keys, query=col

    for (int kt = jlo; kt < jhi; kt += 32) {
        int ktB = kt + 16;
        // ---- issue all loads for both tiles up front ----
        int krowA = kt + col;   if (krowA > NK - 1) krowA = NK - 1;
        int krowB = ktB + col;  if (krowB > NK - 1) krowB = NK - 1;
        bf16x8_t kfA = *(const bf16x8_t*)(k2b + (size_t)krowA * HID + h * DH + quad * 8);
        bf16x8_t kfB = *(const bf16x8_t*)(k2b + (size_t)krowB * HID + h * DH + quad * 8);
        ushort_t vrA[4], vrB[4];
#pragma unroll
        for (int j = 0; j < 4; ++j) {
            int vrowA = kt + quad * 4 + j;   if (vrowA > NK - 1) vrowA = NK - 1;
            int vrowB = ktB + quad * 4 + j;  if (vrowB > NK - 1) vrowB = NK - 1;
            vrA[j] = v2b[(size_t)vrowA * HID + h * DH + col];
            vrB[j] = v2b[(size_t)vrowB * HID + h * DH + col];
        }
        // S tiles: row (quad*4+r) = key, col (lane&15) = query
        f32x4_t SA = __builtin_amdgcn_mfma_f32_16x16x32_bf16(
            kfA, qf, (f32x4_t){0.f, 0.f, 0.f, 0.f}, 0, 0, 0);
        f32x4_t SB = __builtin_amdgcn_mfma_f32_16x16x32_bf16(
            kfB, qf, (f32x4_t){0.f, 0.f, 0.f, 0.f}, 0, 0, 0);

        bf16x4_t pbA, vbA, pbB, vbB;
#pragma unroll
        for (int r = 0; r < 4; ++r) {
            int kkA = kt + quad * 4 + r;
            bool okA = (kkA >= j0q) && (kkA < j1q);
            float pA = okA ? __expf(SA[r] * ATT_SCALE) : 0.f;
            l_st += pA;
            pbA[r] = (short)f_to_bf16_bits(pA);
            vbA[r] = (short)vrA[r];
            int kkB = ktB + quad * 4 + r;
            bool okB = (kkB >= j0q) && (kkB < j1q);
            float pB = okB ? __expf(SB[r] * ATT_SCALE) : 0.f;
            l_st += pB;
            pbB[r] = (short)f_to_bf16_bits(pB);
            vbB[r] = (short)vrB[r];
        }
        accO  = __builtin_amdgcn_mfma_f32_16x16x16bf16_1k(pbA, vbA, accO,  0, 0, 0);
        accO2 = __builtin_amdgcn_mfma_f32_16x16x16bf16_1k(pbB, vbB, accO2, 0, 0, 0);
    }
#pragma unroll
    for (int r = 0; r < 4; ++r) accO[r] += accO2[r];

    // total l per query=col: reduce across the 4 quads
    l_st += __shfl_xor(l_st, 16, 64);
    l_st += __shfl_xor(l_st, 32, 64);

#pragma unroll
    for (int r = 0; r < 4; ++r) {
        int qrow_local = quad * 4 + r;               // accO row = query index
        float lq = __shfl(l_st, qrow_local, 64);     // lane qrow_local has col==qrow_local
        float o = (lq > 0.f) ? accO[r] / lq : 0.f;
        int qrow = q0 + qrow_local;
        ctxb[(size_t)qrow * HID + h * DH + col] = f_to_bf16_bits(o);
    }
}

// ---------------------------------------------------------------------------
// K4: O-projection + residual + LayerNorm fused. 256 blocks x 16 rows (full
// CU coverage; was 64 blocks = only 64/256 CUs). 4 waves each own 4 col-tiles;
// LN row-sums combined across waves via a tiny LDS reduction.
// ---------------------------------------------------------------------------
template <bool F32>
__device__ __forceinline__ void oln_body(KArgs& a, float* ws, int u,
                                         int wv, int col, int quad, int fl) {
    __shared__ float sred[4][16], ssred[4][16];
    const ushort_t* ctxb = (const ushort_t*)(ws + OFF_CTXB);
    const ushort_t* wot  = (const ushort_t*)(ws + OFF_WOT);
    const float* beffO = ws + OFF_BEFF + 3 * 256;

    int m0 = u * 16;
    f32x4_t acc[4];
#pragma unroll
    for (int t = 0; t < 4; ++t) acc[t] = (f32x4_t){0.f, 0.f, 0.f, 0.f};
    const ushort_t* Xrow = ctxb + (size_t)(m0 + col) * 256 + quad * 8;
    const ushort_t* Wbase = wot + (size_t)col * 256 + quad * 8;
#pragma unroll
    for (int kc = 0; kc < 256; kc += 32) {
        bf16x8_t af = *(const bf16x8_t*)(Xrow + kc);
#pragma unroll
        for (int tt = 0; tt < 4; ++tt) {
            int t = wv * 4 + tt;
            bf16x8_t bf = *(const bf16x8_t*)(Wbase + (size_t)t * 16 * 256 + kc);
            acc[tt] = __builtin_amdgcn_mfma_f32_16x16x32_bf16(af, bf, acc[tt], 0, 0, 0);
        }
    }
    float s_[4] = {0.f, 0.f, 0.f, 0.f};
    float ss_[4] = {0.f, 0.f, 0.f, 0.f};
#pragma unroll
    for (int tt = 0; tt < 4; ++tt) {
        int n = (wv * 4 + tt) * 16 + col;
        float b = beffO[n];
#pragma unroll
        for (int rr = 0; rr < 4; ++rr) {
            int m = m0 + quad * 4 + rr;
            float x = acc[tt][rr] + b + ld1f<F32>(a.in[0], (size_t)m * 256 + n);
            acc[tt][rr] = x;
            s_[rr] += x;
            ss_[rr] += x * x;
        }
    }
    // width-16 shuffle: per-wave partial row sums (this wave's 64 cols)
#pragma unroll
    for (int off = 1; off < 16; off <<= 1) {
#pragma unroll
        for (int rr = 0; rr < 4; ++rr) {
            s_[rr]  += __shfl_xor(s_[rr],  off, 16);
            ss_[rr] += __shfl_xor(ss_[rr], off, 16);
        }
    }
    if (col == 0) {
#pragma unroll
        for (int rr = 0; rr < 4; ++rr) {
            sred[wv][quad * 4 + rr]  = s_[rr];
            ssred[wv][quad * 4 + rr] = ss_[rr];
        }
    }
    __syncthreads();
    float mu[4], inv[4];
#pragma unroll
    for (int rr = 0; rr < 4; ++rr) {
        int row = quad * 4 + rr;
        float ts  = sred[0][row]  + sred[1][row]  + sred[2][row]  + sred[3][row];
        float tss = ssred[0][row] + ssred[1][row] + ssred[2][row] + ssred[3][row];
        mu[rr] = ts * (1.f / QD);
        float var = tss * (1.f / QD) - mu[rr] * mu[rr];
        inv[rr] = rsqrtf(var + LN_EPS);
    }
#pragma unroll
    for (int tt = 0; tt < 4; ++tt) {
        int n = (wv * 4 + tt) * 16 + col;
        float g = ld1f<F32>(a.in[14], n), bb = ld1f<F32>(a.in[15], n);
#pragma unroll
        for (int rr = 0; rr < 4; ++rr) {
            int m = m0 + quad * 4 + rr;
            float y = (acc[tt][rr] - mu[rr]) * inv[rr] * g + bb;
            size_t idx = (size_t)m * 256 + n;
            if (fl) ((ushort_t*)a.out)[idx] = f_to_bf16_bits(y);
            else    ((float*)a.out)[idx] = y;
        }
    }
}

__global__ __launch_bounds__(256) void k_oln(KArgs a) {
    float* ws = a.ws;
    const int tid = threadIdx.x;
    const int lane = tid & 63, wv = tid >> 6;
    const int col = lane & 15, quad = lane >> 4;
    const int fl = *(const int*)(ws + OFF_FLAG);
    if (fl) oln_body<false>(a, ws, blockIdx.x, wv, col, quad, fl);
    else    oln_body<true >(a, ws, blockIdx.x, wv, col, quad, fl);
}

extern "C" void kernel_launch(void* const* d_in, const int* in_sizes, int n_in,
                              void* d_out, int out_size, void* d_ws, size_t ws_size,
                              hipStream_t stream) {
    KArgs a;
    for (int i = 0; i < 18; ++i) a.in[i] = d_in[i];
    a.ws = (float*)d_ws;
    a.out = d_out;

    k_fuse<<<92, 256, 0, stream>>>(a);
    k_qkv<<<768, 256, 0, stream>>>(a);
    k_attn<<<512, 256, 0, stream>>>(a);
    k_oln<<<256, 256, 0, stream>>>(a);
}

// Round 9
// 145.630 us; speedup vs baseline: 3.5571x; 1.0181x over previous
//
#include <hip/hip_runtime.h>
#include <hip/hip_bf16.h>
#include <math.h>

#define NQ 4096
#define NK 4096
#define QD 256
#define KD 320
#define HID 256
#define NH 8
#define DH 32
#define NB 16
#define LN_EPS 1e-5f
#define ATT_SCALE 0.17677669529663687f   // 1/sqrt(32)

typedef unsigned short ushort_t;
typedef __attribute__((ext_vector_type(8))) short bf16x8_t;
typedef __attribute__((ext_vector_type(4))) short bf16x4_t;
typedef __attribute__((ext_vector_type(4))) float f32x4_t;

// ---------------------------------------------------------------------------
// ws layout (float offsets), ~9 MB. ctxb region is now only READ (poison
// pattern) to seed the LDS ctx tile — preserves exact legacy values for any
// column the attention phase does not cover.
// ---------------------------------------------------------------------------
#define OFF_Q2B   0         // bf16 [4096][256]
#define OFF_K2B   524288    // bf16 [4096][256]
#define OFF_V2B   1048576   // bf16 [4096][256]
#define OFF_CTXB  1572864   // bf16 [4096][256] (legacy; read-only seed now)
#define OFF_WQT   2097152   // bf16 WeffQT [256][256]
#define OFF_WKT   2129920   // bf16 WeffKT [256][320]
#define OFF_WVT   2170880   // bf16 WeffVT [256][320]
#define OFF_WOT   2211840   // bf16 WeffOT [256][256]
#define OFF_BEFF  2244608   // f32 [4][256]: Q,K,V,O
#define OFF_KST   2245632   // 16 int
#define OFF_KEN   2245648   // 16 int
#define OFF_FLAG  2245664   // 1 int

struct KArgs {
    const void* in[18];
    float* ws;
    void* out;
};

__device__ __forceinline__ float bf16_bits_to_f(ushort_t s) {
    unsigned int u = (unsigned int)s << 16;
    float f;
    __builtin_memcpy(&f, &u, 4);
    return f;
}

__device__ __forceinline__ ushort_t f_to_bf16_bits(float v) {
    __hip_bfloat16 t = (__hip_bfloat16)v;
    ushort_t b;
    __builtin_memcpy(&b, &t, 2);
    return b;
}

// dtype-generic loaders: F32=false -> input is bf16; F32=true -> input is f32
template <bool F32>
__device__ __forceinline__ bf16x8_t ld8(const void* p, size_t idx) {
    if constexpr (!F32) {
        return *(const bf16x8_t*)((const ushort_t*)p + idx);
    } else {
        f32x4_t f0 = *(const f32x4_t*)((const float*)p + idx);
        f32x4_t f1 = *(const f32x4_t*)((const float*)p + idx + 4);
        bf16x8_t h;
#pragma unroll
        for (int e = 0; e < 4; ++e) h[e] = (short)f_to_bf16_bits(f0[e]);
#pragma unroll
        for (int e = 0; e < 4; ++e) h[4 + e] = (short)f_to_bf16_bits(f1[e]);
        return h;
    }
}

template <bool F32>
__device__ __forceinline__ float ld1f(const void* p, size_t idx) {
    if constexpr (F32) return ((const float*)p)[idx];
    else               return bf16_bits_to_f(((const ushort_t*)p)[idx]);
}

template <bool F32>
__device__ __forceinline__ ushort_t ld1h(const void* p, size_t idx) {
    if constexpr (F32) return f_to_bf16_bits(((const float*)p)[idx]);
    else               return ((const ushort_t*)p)[idx];
}

// per-block dtype probe on first 8KB of query_nodes (in-bounds either way)
__device__ __forceinline__ int detect_flag(const void* probe_v, int tid) {
    __shared__ float s_red[4];
    const ushort_t* probe = (const ushort_t*)probe_v;
    float mx = 0.f;
    for (int i = tid; i < 4096; i += 256) {
        float f = fabsf(bf16_bits_to_f(probe[i]));
        if (!(f == f)) f = 1e38f;
        mx = fmaxf(mx, f);
    }
    for (int off = 32; off; off >>= 1) mx = fmaxf(mx, __shfl_xor(mx, off, 64));
    if ((tid & 63) == 0) s_red[tid >> 6] = mx;
    __syncthreads();
    float m2 = fmaxf(fmaxf(s_red[0], s_red[1]), fmaxf(s_red[2], s_red[3]));
    __syncthreads();
    return (m2 < 100.f) ? 1 : 0;
}

// ---------------------------------------------------------------------------
// K1: ranges (blocks 0..15) + weight-fusion GEMMs (16..87) + biases (88..91)
// ---------------------------------------------------------------------------
template <bool F32>
__device__ __forceinline__ void fuse_qkv_tile(const void* A, size_t abase,
                                              const void* B, ushort_t* Out,
                                              int N, int m0, int n0,
                                              int col, int quad) {
    f32x4_t acc[4];
#pragma unroll
    for (int t = 0; t < 4; ++t) acc[t] = (f32x4_t){0.f, 0.f, 0.f, 0.f};
    size_t aoff = abase + (size_t)(m0 + col) * 256 + quad * 8;
    size_t boff = (size_t)(n0 + col) * 256 + quad * 8;
#pragma unroll
    for (int kc = 0; kc < 256; kc += 32) {
        bf16x8_t af = ld8<F32>(A, aoff + kc);
#pragma unroll
        for (int t = 0; t < 4; ++t) {
            bf16x8_t bf = ld8<F32>(B, boff + (size_t)t * 16 * 256 + kc);
            acc[t] = __builtin_amdgcn_mfma_f32_16x16x32_bf16(af, bf, acc[t], 0, 0, 0);
        }
    }
#pragma unroll
    for (int t = 0; t < 4; ++t)
#pragma unroll
        for (int rr = 0; rr < 4; ++rr)
            Out[(size_t)(m0 + quad * 4 + rr) * N + n0 + t * 16 + col] =
                f_to_bf16_bits(acc[t][rr]);
}

// WeffOT[n][k'] = sum_j Wo[j][n] * mow[k'][j]  (A-frag gathered from Wo cols)
template <bool F32>
__device__ __forceinline__ void fuse_o_tile(const void* Wo, const void* Mow,
                                            ushort_t* Out, int m0, int n0,
                                            int col, int quad) {
    f32x4_t acc[4];
#pragma unroll
    for (int t = 0; t < 4; ++t) acc[t] = (f32x4_t){0.f, 0.f, 0.f, 0.f};
#pragma unroll
    for (int kc = 0; kc < 256; kc += 32) {
        bf16x8_t af;
#pragma unroll
        for (int t = 0; t < 8; ++t)
            af[t] = (short)ld1h<F32>(Wo, (size_t)(kc + quad * 8 + t) * 256 + m0 + col);
#pragma unroll
        for (int t = 0; t < 4; ++t) {
            bf16x8_t bf = ld8<F32>(Mow, (size_t)(n0 + t * 16 + col) * 256 + quad * 8 + kc);
            acc[t] = __builtin_amdgcn_mfma_f32_16x16x32_bf16(af, bf, acc[t], 0, 0, 0);
        }
    }
#pragma unroll
    for (int t = 0; t < 4; ++t)
#pragma unroll
        for (int rr = 0; rr < 4; ++rr)
            Out[(size_t)(m0 + quad * 4 + rr) * 256 + n0 + t * 16 + col] =
                f_to_bf16_bits(acc[t][rr]);
}

template <bool F32>
__device__ __forceinline__ void bias_body(KArgs& a, float* ws, int m, int tid) {
    __shared__ float bsh[256];
    float* beff = ws + OFF_BEFF;
    if (m < 3) {
        const void* bsrc = (m == 0) ? a.in[3] : (m == 1) ? a.in[5] : a.in[7];
        bsh[tid] = ld1f<F32>(bsrc, tid);
        __syncthreads();
        float acc = 0.f;
        size_t row = (size_t)(m * 256 + tid) * 256;
#pragma unroll 4
        for (int kc = 0; kc < 256; kc += 8) {
            bf16x8_t wr = ld8<F32>(a.in[8], row + kc);
#pragma unroll
            for (int t = 0; t < 8; ++t)
                acc += bsh[kc + t] * bf16_bits_to_f((ushort_t)wr[t]);
        }
        acc += ld1f<F32>(a.in[9], m * 256 + tid);
        beff[m * 256 + tid] = acc;
    } else {
        bsh[tid] = ld1f<F32>(a.in[11], tid);   // mha_ob
        __syncthreads();
        float acc = 0.f;
        for (int k = 0; k < 256; ++k)
            acc += bsh[k] * ld1f<F32>(a.in[12], (size_t)k * 256 + tid);  // Wo[k][j]
        acc += ld1f<F32>(a.in[13], tid);
        beff[3 * 256 + tid] = acc;
    }
}

__global__ __launch_bounds__(256) void k_fuse(KArgs a) {
    float* ws = a.ws;
    const int tid = threadIdx.x, bid = blockIdx.x;
    const int lane = tid & 63, wv = tid >> 6;
    const int col = lane & 15, quad = lane >> 4;
    int fl = detect_flag(a.in[0], tid);
    if (bid == 0 && tid == 0) *(int*)(ws + OFF_FLAG) = fl;

    if (bid < 16) {
        // batch ranges from sorted key_batch_idx (boundary detection)
        const int* kb = (const int*)a.in[17];
        int* kstart = (int*)(ws + OFF_KST);
        int* kend   = (int*)(ws + OFF_KEN);
        int j = bid * 256 + tid;
        if (j < NK) {
            int b = kb[j];
            if (j == 0) {
                for (int x = 0; x < b; ++x) { kstart[x] = 0; kend[x] = 0; }
                kstart[b] = 0;
            } else {
                int bp = kb[j - 1];
                if (bp != b) {
                    kend[bp] = j;
                    for (int x = bp + 1; x < b; ++x) { kstart[x] = j; kend[x] = j; }
                    kstart[b] = j;
                }
            }
            if (j == NK - 1) {
                kend[b] = NK;
                for (int x = b + 1; x < NB; ++x) { kstart[x] = NK; kend[x] = NK; }
            }
        }
    } else if (bid < 88) {
        int r = bid - 16;
        const void* A; const void* B; ushort_t* Out;
        size_t abase; int N, mb, nb, typ;
        if (r < 16)      { typ = 0; A = a.in[8]; abase = 0;      B = a.in[2]; Out = (ushort_t*)(ws + OFF_WQT); N = 256; mb = r >> 2; nb = r & 3; }
        else if (r < 36) { typ = 0; int rr = r - 16; A = a.in[8]; abase = 65536;  B = a.in[4]; Out = (ushort_t*)(ws + OFF_WKT); N = 320; mb = rr / 5; nb = rr % 5; }
        else if (r < 56) { typ = 0; int rr = r - 36; A = a.in[8]; abase = 131072; B = a.in[6]; Out = (ushort_t*)(ws + OFF_WVT); N = 320; mb = rr / 5; nb = rr % 5; }
        else             { typ = 1; int rr = r - 56; A = a.in[12]; abase = 0; B = a.in[10]; Out = (ushort_t*)(ws + OFF_WOT); N = 256; mb = rr >> 2; nb = rr & 3; }
        int m0 = mb * 64 + wv * 16, n0 = nb * 64;
        if (typ == 0) {
            if (fl) fuse_qkv_tile<false>(A, abase, B, Out, N, m0, n0, col, quad);
            else    fuse_qkv_tile<true >(A, abase, B, Out, N, m0, n0, col, quad);
        } else {
            if (fl) fuse_o_tile<false>(A, B, Out, m0, n0, col, quad);
            else    fuse_o_tile<true >(A, B, Out, m0, n0, col, quad);
        }
    } else {
        int m = bid - 88;
        if (fl) bias_body<false>(a, ws, m, tid);
        else    bias_body<true >(a, ws, m, tid);
    }
}

// ---------------------------------------------------------------------------
// K2: Q/K/V projections, 768 blocks x 4 waves (12 waves/CU; each block reads
// a 64-row weight quarter, not the whole matrix).
// ---------------------------------------------------------------------------
template <bool F32, int KK>
__device__ __forceinline__ void proj_body(const void* X, const ushort_t* WT,
                                          const float* bias, ushort_t* Z,
                                          int m0, int n0, int col, int quad) {
    f32x4_t acc[4];
#pragma unroll
    for (int t = 0; t < 4; ++t) acc[t] = (f32x4_t){0.f, 0.f, 0.f, 0.f};
    size_t aoff = (size_t)(m0 + col) * KK + quad * 8;
    const ushort_t* Wrow = WT + (size_t)(n0 + col) * KK + quad * 8;
#pragma unroll
    for (int kc = 0; kc < KK; kc += 32) {
        bf16x8_t af = ld8<F32>(X, aoff + kc);
#pragma unroll
        for (int t = 0; t < 4; ++t) {
            bf16x8_t bf = *(const bf16x8_t*)(Wrow + (size_t)t * 16 * KK + kc);
            acc[t] = __builtin_amdgcn_mfma_f32_16x16x32_bf16(af, bf, acc[t], 0, 0, 0);
        }
    }
#pragma unroll
    for (int t = 0; t < 4; ++t)
#pragma unroll
        for (int rr = 0; rr < 4; ++rr) {
            int n = n0 + t * 16 + col;
            Z[(size_t)(m0 + quad * 4 + rr) * 256 + n] =
                f_to_bf16_bits(acc[t][rr] + bias[n]);
        }
}

__global__ __launch_bounds__(256) void k_qkv(KArgs a) {
    float* ws = a.ws;
    const int tid = threadIdx.x, u = blockIdx.x;
    const int lane = tid & 63, wv = tid >> 6;
    const int col = lane & 15, quad = lane >> 4;
    const int fl = *(const int*)(ws + OFF_FLAG);
    const float* beff = ws + OFF_BEFF;

    if (u < 256) {
        int m0 = (u >> 2) * 64 + wv * 16, n0 = (u & 3) * 64;
        const ushort_t* WT = (const ushort_t*)(ws + OFF_WQT);
        ushort_t* Z = (ushort_t*)(ws + OFF_Q2B);
        if (fl) proj_body<false, 256>(a.in[0], WT, beff, Z, m0, n0, col, quad);
        else    proj_body<true , 256>(a.in[0], WT, beff, Z, m0, n0, col, quad);
    } else if (u < 512) {
        int uu = u - 256;
        int m0 = (uu >> 2) * 64 + wv * 16, n0 = (uu & 3) * 64;
        const ushort_t* WT = (const ushort_t*)(ws + OFF_WKT);
        ushort_t* Z = (ushort_t*)(ws + OFF_K2B);
        if (fl) proj_body<false, 320>(a.in[1], WT, beff + 256, Z, m0, n0, col, quad);
        else    proj_body<true , 320>(a.in[1], WT, beff + 256, Z, m0, n0, col, quad);
    } else {
        int uu = u - 512;
        int m0 = (uu >> 2) * 64 + wv * 16, n0 = (uu & 3) * 64;
        const ushort_t* WT = (const ushort_t*)(ws + OFF_WVT);
        ushort_t* Z = (ushort_t*)(ws + OFF_V2B);
        if (fl) proj_body<false, 320>(a.in[1], WT, beff + 512, Z, m0, n0, col, quad);
        else    proj_body<true , 320>(a.in[1], WT, beff + 512, Z, m0, n0, col, quad);
    }
}

// ---------------------------------------------------------------------------
// K3: attention + O-projection + residual + LayerNorm, fully fused.
// 256 blocks x 512 threads (8 waves = 8 heads, one qt tile of 16 queries per
// block). ctx tile lives in LDS; it is SEEDED from the legacy ctxb ws region
// (poison pattern) so any column the attention phase does not write reads
// exactly what the old k_oln saw — bit-identical behavior to the 4-kernel
// pipeline. After a barrier, the same block performs O-proj + residual + LN.
// ---------------------------------------------------------------------------
#define CTXP 264   // padded row length (+8 bf16 = +16B) -> 2-way banks, free

template <bool F32>
__device__ __forceinline__ void oln_part(KArgs& a, float* ws,
                                         const ushort_t ctxl[16][CTXP],
                                         float sred[8][16], float ssred[8][16],
                                         int q0, int wv, int col, int quad,
                                         int fl) {
    const ushort_t* wot  = (const ushort_t*)(ws + OFF_WOT);
    const float* beffO = ws + OFF_BEFF + 3 * 256;

    f32x4_t acc[2];
#pragma unroll
    for (int t = 0; t < 2; ++t) acc[t] = (f32x4_t){0.f, 0.f, 0.f, 0.f};
    const ushort_t* Wbase = wot + (size_t)col * 256 + quad * 8;
#pragma unroll
    for (int kc = 0; kc < 256; kc += 32) {
        bf16x8_t af = *(const bf16x8_t*)(&ctxl[col][quad * 8 + kc]);
#pragma unroll
        for (int tt = 0; tt < 2; ++tt) {
            int t = wv * 2 + tt;
            bf16x8_t bf = *(const bf16x8_t*)(Wbase + (size_t)t * 16 * 256 + kc);
            acc[tt] = __builtin_amdgcn_mfma_f32_16x16x32_bf16(af, bf, acc[tt], 0, 0, 0);
        }
    }
    float s_[4] = {0.f, 0.f, 0.f, 0.f};
    float ss_[4] = {0.f, 0.f, 0.f, 0.f};
#pragma unroll
    for (int tt = 0; tt < 2; ++tt) {
        int n = (wv * 2 + tt) * 16 + col;
        float b = beffO[n];
#pragma unroll
        for (int rr = 0; rr < 4; ++rr) {
            int m = q0 + quad * 4 + rr;
            float x = acc[tt][rr] + b + ld1f<F32>(a.in[0], (size_t)m * 256 + n);
            acc[tt][rr] = x;
            s_[rr] += x;
            ss_[rr] += x * x;
        }
    }
    // width-16 shuffle: partial row sums over this wave's 32 cols
#pragma unroll
    for (int off = 1; off < 16; off <<= 1) {
#pragma unroll
        for (int rr = 0; rr < 4; ++rr) {
            s_[rr]  += __shfl_xor(s_[rr],  off, 16);
            ss_[rr] += __shfl_xor(ss_[rr], off, 16);
        }
    }
    if (col == 0) {
#pragma unroll
        for (int rr = 0; rr < 4; ++rr) {
            sred[wv][quad * 4 + rr]  = s_[rr];
            ssred[wv][quad * 4 + rr] = ss_[rr];
        }
    }
    __syncthreads();
    float mu[4], inv[4];
#pragma unroll
    for (int rr = 0; rr < 4; ++rr) {
        int row = quad * 4 + rr;
        float ts = 0.f, tss = 0.f;
#pragma unroll
        for (int w = 0; w < 8; ++w) { ts += sred[w][row]; tss += ssred[w][row]; }
        mu[rr] = ts * (1.f / QD);
        float var = tss * (1.f / QD) - mu[rr] * mu[rr];
        inv[rr] = rsqrtf(var + LN_EPS);
    }
#pragma unroll
    for (int tt = 0; tt < 2; ++tt) {
        int n = (wv * 2 + tt) * 16 + col;
        float g = ld1f<F32>(a.in[14], n), bb = ld1f<F32>(a.in[15], n);
#pragma unroll
        for (int rr = 0; rr < 4; ++rr) {
            int m = q0 + quad * 4 + rr;
            float y = (acc[tt][rr] - mu[rr]) * inv[rr] * g + bb;
            size_t idx = (size_t)m * 256 + n;
            if (fl) ((ushort_t*)a.out)[idx] = f_to_bf16_bits(y);
            else    ((float*)a.out)[idx] = y;
        }
    }
}

__global__ __launch_bounds__(512) void k_attn_oln(KArgs a) {
    __shared__ ushort_t ctxl[16][CTXP];
    __shared__ float sred[8][16], ssred[8][16];
    float* ws = a.ws;
    const ushort_t* q2b = (const ushort_t*)(ws + OFF_Q2B);
    const ushort_t* k2b = (const ushort_t*)(ws + OFF_K2B);
    const ushort_t* v2b = (const ushort_t*)(ws + OFF_V2B);
    const ushort_t* ctxb = (const ushort_t*)(ws + OFF_CTXB);
    const int* qb  = (const int*)a.in[16];
    const int* kst = (const int*)(ws + OFF_KST);
    const int* ken = (const int*)(ws + OFF_KEN);

    const int tid = threadIdx.x;
    const int lane = tid & 63, wv = tid >> 6;     // wv = head 0..7
    const int col = lane & 15, quad = lane >> 4;
    const int fl = *(const int*)(ws + OFF_FLAG);
    const int qt = blockIdx.x;
    const int q0 = qt * 16;
    const int h  = wv;

    // seed ctx tile from legacy ctxb region (preserves stale-col semantics);
    // one bf16x8 per thread: 512 * 8 = 16 * 256
    {
        int m = tid >> 5, nblk = (tid & 31) * 8;
        *(bf16x8_t*)(&ctxl[m][nblk]) =
            *(const bf16x8_t*)(ctxb + (size_t)(q0 + m) * 256 + nblk);
    }
    __syncthreads();

    // ------------------------- attention phase ---------------------------
    {
        int qq = q0 + col;
        int bq_ = qb[qq];
        int j0q = kst[bq_], j1q = ken[bq_];
        int jlo = j0q, jhi = j1q;
#pragma unroll
        for (int off = 1; off < 16; off <<= 1) {
            jlo = min(jlo, __shfl_xor(jlo, off, 64));
            jhi = max(jhi, __shfl_xor(jhi, off, 64));
        }

        bf16x8_t qf = *(const bf16x8_t*)(q2b + (size_t)qq * HID + h * DH + quad * 8);

        f32x4_t accO  = {0.f, 0.f, 0.f, 0.f};
        f32x4_t accO2 = {0.f, 0.f, 0.f, 0.f};
        float l_st = 0.f;   // per-lane partial: sum over this lane's keys, query=col

        for (int kt = jlo; kt < jhi; kt += 32) {
            int ktB = kt + 16;
            int krowA = kt + col;   if (krowA > NK - 1) krowA = NK - 1;
            int krowB = ktB + col;  if (krowB > NK - 1) krowB = NK - 1;
            bf16x8_t kfA = *(const bf16x8_t*)(k2b + (size_t)krowA * HID + h * DH + quad * 8);
            bf16x8_t kfB = *(const bf16x8_t*)(k2b + (size_t)krowB * HID + h * DH + quad * 8);
            ushort_t vrA[4], vrB[4];
#pragma unroll
            for (int j = 0; j < 4; ++j) {
                int vrowA = kt + quad * 4 + j;   if (vrowA > NK - 1) vrowA = NK - 1;
                int vrowB = ktB + quad * 4 + j;  if (vrowB > NK - 1) vrowB = NK - 1;
                vrA[j] = v2b[(size_t)vrowA * HID + h * DH + col];
                vrB[j] = v2b[(size_t)vrowB * HID + h * DH + col];
            }
            // S tile: row (quad*4+r) = key, col (lane&15) = query
            f32x4_t SA = __builtin_amdgcn_mfma_f32_16x16x32_bf16(
                kfA, qf, (f32x4_t){0.f, 0.f, 0.f, 0.f}, 0, 0, 0);
            f32x4_t SB = __builtin_amdgcn_mfma_f32_16x16x32_bf16(
                kfB, qf, (f32x4_t){0.f, 0.f, 0.f, 0.f}, 0, 0, 0);

            bf16x4_t pbA, vbA, pbB, vbB;
#pragma unroll
            for (int r = 0; r < 4; ++r) {
                int kkA = kt + quad * 4 + r;
                bool okA = (kkA >= j0q) && (kkA < j1q);
                float pA = okA ? __expf(SA[r] * ATT_SCALE) : 0.f;
                l_st += pA;
                pbA[r] = (short)f_to_bf16_bits(pA);
                vbA[r] = (short)vrA[r];
                int kkB = ktB + quad * 4 + r;
                bool okB = (kkB >= j0q) && (kkB < j1q);
                float pB = okB ? __expf(SB[r] * ATT_SCALE) : 0.f;
                l_st += pB;
                pbB[r] = (short)f_to_bf16_bits(pB);
                vbB[r] = (short)vrB[r];
            }
            accO  = __builtin_amdgcn_mfma_f32_16x16x16bf16_1k(pbA, vbA, accO,  0, 0, 0);
            accO2 = __builtin_amdgcn_mfma_f32_16x16x16bf16_1k(pbB, vbB, accO2, 0, 0, 0);
        }
#pragma unroll
        for (int r = 0; r < 4; ++r) accO[r] += accO2[r];

        // total l per query=col: reduce across the 4 quads
        l_st += __shfl_xor(l_st, 16, 64);
        l_st += __shfl_xor(l_st, 32, 64);

#pragma unroll
        for (int r = 0; r < 4; ++r) {
            int qrow_local = quad * 4 + r;               // accO row = query index
            float lq = __shfl(l_st, qrow_local, 64);     // lane qrow_local has col==qrow_local
            float o = (lq > 0.f) ? accO[r] / lq : 0.f;
            ctxl[qrow_local][h * DH + col] = f_to_bf16_bits(o);
        }
    }
    __syncthreads();

    // ---------------- O-projection + residual + LayerNorm -----------------
    if (fl) oln_part<false>(a, ws, ctxl, sred, ssred, q0, wv, col, quad, fl);
    else    oln_part<true >(a, ws, ctxl, sred, ssred, q0, wv, col, quad, fl);
}

extern "C" void kernel_launch(void* const* d_in, const int* in_sizes, int n_in,
                              void* d_out, int out_size, void* d_ws, size_t ws_size,
                              hipStream_t stream) {
    KArgs a;
    for (int i = 0; i < 18; ++i) a.in[i] = d_in[i];
    a.ws = (float*)d_ws;
    a.out = d_out;

    k_fuse<<<92, 256, 0, stream>>>(a);
    k_qkv<<<768, 256, 0, stream>>>(a);
    k_attn_oln<<<256, 512, 0, stream>>>(a);
}

// Round 14
// 138.108 us; speedup vs baseline: 3.7508x; 1.0545x over previous
//
#include <hip/hip_runtime.h>
#include <hip/hip_bf16.h>
#include <math.h>

#define NQ 4096
#define NK 4096
#define QD 256
#define KD 320
#define HID 256
#define NH 8
#define DH 32
#define NB 16
#define LN_EPS 1e-5f
#define ATT_SCALE 0.17677669529663687f   // 1/sqrt(32)

typedef unsigned short ushort_t;
typedef __attribute__((ext_vector_type(8))) short bf16x8_t;
typedef __attribute__((ext_vector_type(4))) short bf16x4_t;
typedef __attribute__((ext_vector_type(4))) float f32x4_t;

// ---------------------------------------------------------------------------
// ws layout (float offsets), ~9 MB.
// ---------------------------------------------------------------------------
#define OFF_Q2B   0         // bf16 [4096][256]
#define OFF_K2B   524288    // bf16 [4096][256]
#define OFF_V2B   1048576   // bf16 [4096][256]
#define OFF_CTXB  1572864   // bf16 [4096][256] (legacy; read-only seed now)
#define OFF_WQT   2097152   // bf16 WeffQT [256][256]
#define OFF_WKT   2129920   // bf16 WeffKT [256][320]
#define OFF_WVT   2170880   // bf16 WeffVT [256][320]
#define OFF_WOT   2211840   // bf16 WeffOT [256][256]
#define OFF_BEFF  2244608   // f32 [4][256]: Q,K,V,O
#define OFF_KST   2245632   // 16 int
#define OFF_KEN   2245648   // 16 int
#define OFF_FLAG  2245664   // 1 int

struct KArgs {
    const void* in[18];
    float* ws;
    void* out;
};

__device__ __forceinline__ float bf16_bits_to_f(ushort_t s) {
    unsigned int u = (unsigned int)s << 16;
    float f;
    __builtin_memcpy(&f, &u, 4);
    return f;
}

__device__ __forceinline__ ushort_t f_to_bf16_bits(float v) {
    __hip_bfloat16 t = (__hip_bfloat16)v;
    ushort_t b;
    __builtin_memcpy(&b, &t, 2);
    return b;
}

// dtype-generic loaders: F32=false -> input is bf16; F32=true -> input is f32
template <bool F32>
__device__ __forceinline__ bf16x8_t ld8(const void* p, size_t idx) {
    if constexpr (!F32) {
        return *(const bf16x8_t*)((const ushort_t*)p + idx);
    } else {
        f32x4_t f0 = *(const f32x4_t*)((const float*)p + idx);
        f32x4_t f1 = *(const f32x4_t*)((const float*)p + idx + 4);
        bf16x8_t h;
#pragma unroll
        for (int e = 0; e < 4; ++e) h[e] = (short)f_to_bf16_bits(f0[e]);
#pragma unroll
        for (int e = 0; e < 4; ++e) h[4 + e] = (short)f_to_bf16_bits(f1[e]);
        return h;
    }
}

template <bool F32>
__device__ __forceinline__ float ld1f(const void* p, size_t idx) {
    if constexpr (F32) return ((const float*)p)[idx];
    else               return bf16_bits_to_f(((const ushort_t*)p)[idx]);
}

template <bool F32>
__device__ __forceinline__ ushort_t ld1h(const void* p, size_t idx) {
    if constexpr (F32) return f_to_bf16_bits(((const float*)p)[idx]);
    else               return ((const ushort_t*)p)[idx];
}

// per-block dtype probe on first 8KB of query_nodes (in-bounds either way)
__device__ __forceinline__ int detect_flag(const void* probe_v, int tid) {
    __shared__ float s_red[4];
    const ushort_t* probe = (const ushort_t*)probe_v;
    float mx = 0.f;
    for (int i = tid; i < 4096; i += 256) {
        float f = fabsf(bf16_bits_to_f(probe[i]));
        if (!(f == f)) f = 1e38f;
        mx = fmaxf(mx, f);
    }
    for (int off = 32; off; off >>= 1) mx = fmaxf(mx, __shfl_xor(mx, off, 64));
    if ((tid & 63) == 0) s_red[tid >> 6] = mx;
    __syncthreads();
    float m2 = fmaxf(fmaxf(s_red[0], s_red[1]), fmaxf(s_red[2], s_red[3]));
    __syncthreads();
    return (m2 < 100.f) ? 1 : 0;
}

// ---------------------------------------------------------------------------
// K1: ranges (blocks 0..15) + weight-fusion GEMMs (16..87) + biases (88..91)
// ---------------------------------------------------------------------------
template <bool F32>
__device__ __forceinline__ void fuse_qkv_tile(const void* A, size_t abase,
                                              const void* B, ushort_t* Out,
                                              int N, int m0, int n0,
                                              int col, int quad) {
    f32x4_t acc[4];
#pragma unroll
    for (int t = 0; t < 4; ++t) acc[t] = (f32x4_t){0.f, 0.f, 0.f, 0.f};
    size_t aoff = abase + (size_t)(m0 + col) * 256 + quad * 8;
    size_t boff = (size_t)(n0 + col) * 256 + quad * 8;
#pragma unroll
    for (int kc = 0; kc < 256; kc += 32) {
        bf16x8_t af = ld8<F32>(A, aoff + kc);
#pragma unroll
        for (int t = 0; t < 4; ++t) {
            bf16x8_t bf = ld8<F32>(B, boff + (size_t)t * 16 * 256 + kc);
            acc[t] = __builtin_amdgcn_mfma_f32_16x16x32_bf16(af, bf, acc[t], 0, 0, 0);
        }
    }
#pragma unroll
    for (int t = 0; t < 4; ++t)
#pragma unroll
        for (int rr = 0; rr < 4; ++rr)
            Out[(size_t)(m0 + quad * 4 + rr) * N + n0 + t * 16 + col] =
                f_to_bf16_bits(acc[t][rr]);
}

// WeffOT[n][k'] = sum_j Wo[j][n] * mow[k'][j]  (A-frag gathered from Wo cols)
template <bool F32>
__device__ __forceinline__ void fuse_o_tile(const void* Wo, const void* Mow,
                                            ushort_t* Out, int m0, int n0,
                                            int col, int quad) {
    f32x4_t acc[4];
#pragma unroll
    for (int t = 0; t < 4; ++t) acc[t] = (f32x4_t){0.f, 0.f, 0.f, 0.f};
#pragma unroll
    for (int kc = 0; kc < 256; kc += 32) {
        bf16x8_t af;
#pragma unroll
        for (int t = 0; t < 8; ++t)
            af[t] = (short)ld1h<F32>(Wo, (size_t)(kc + quad * 8 + t) * 256 + m0 + col);
#pragma unroll
        for (int t = 0; t < 4; ++t) {
            bf16x8_t bf = ld8<F32>(Mow, (size_t)(n0 + t * 16 + col) * 256 + quad * 8 + kc);
            acc[t] = __builtin_amdgcn_mfma_f32_16x16x32_bf16(af, bf, acc[t], 0, 0, 0);
        }
    }
#pragma unroll
    for (int t = 0; t < 4; ++t)
#pragma unroll
        for (int rr = 0; rr < 4; ++rr)
            Out[(size_t)(m0 + quad * 4 + rr) * 256 + n0 + t * 16 + col] =
                f_to_bf16_bits(acc[t][rr]);
}

template <bool F32>
__device__ __forceinline__ void bias_body(KArgs& a, float* ws, int m, int tid) {
    __shared__ float bsh[256];
    float* beff = ws + OFF_BEFF;
    if (m < 3) {
        const void* bsrc = (m == 0) ? a.in[3] : (m == 1) ? a.in[5] : a.in[7];
        bsh[tid] = ld1f<F32>(bsrc, tid);
        __syncthreads();
        float acc = 0.f;
        size_t row = (size_t)(m * 256 + tid) * 256;
#pragma unroll 4
        for (int kc = 0; kc < 256; kc += 8) {
            bf16x8_t wr = ld8<F32>(a.in[8], row + kc);
#pragma unroll
            for (int t = 0; t < 8; ++t)
                acc += bsh[kc + t] * bf16_bits_to_f((ushort_t)wr[t]);
        }
        acc += ld1f<F32>(a.in[9], m * 256 + tid);
        beff[m * 256 + tid] = acc;
    } else {
        bsh[tid] = ld1f<F32>(a.in[11], tid);   // mha_ob
        __syncthreads();
        float acc = 0.f;
        for (int k = 0; k < 256; ++k)
            acc += bsh[k] * ld1f<F32>(a.in[12], (size_t)k * 256 + tid);  // Wo[k][j]
        acc += ld1f<F32>(a.in[13], tid);
        beff[3 * 256 + tid] = acc;
    }
}

__global__ __launch_bounds__(256) void k_fuse(KArgs a) {
    float* ws = a.ws;
    const int tid = threadIdx.x, bid = blockIdx.x;
    const int lane = tid & 63, wv = tid >> 6;
    const int col = lane & 15, quad = lane >> 4;
    int fl = detect_flag(a.in[0], tid);
    if (bid == 0 && tid == 0) *(int*)(ws + OFF_FLAG) = fl;

    if (bid < 16) {
        // batch ranges from sorted key_batch_idx (boundary detection)
        const int* kb = (const int*)a.in[17];
        int* kstart = (int*)(ws + OFF_KST);
        int* kend   = (int*)(ws + OFF_KEN);
        int j = bid * 256 + tid;
        if (j < NK) {
            int b = kb[j];
            if (j == 0) {
                for (int x = 0; x < b; ++x) { kstart[x] = 0; kend[x] = 0; }
                kstart[b] = 0;
            } else {
                int bp = kb[j - 1];
                if (bp != b) {
                    kend[bp] = j;
                    for (int x = bp + 1; x < b; ++x) { kstart[x] = j; kend[x] = j; }
                    kstart[b] = j;
                }
            }
            if (j == NK - 1) {
                kend[b] = NK;
                for (int x = b + 1; x < NB; ++x) { kstart[x] = NK; kend[x] = NK; }
            }
        }
    } else if (bid < 88) {
        int r = bid - 16;
        const void* A; const void* B; ushort_t* Out;
        size_t abase; int N, mb, nb, typ;
        if (r < 16)      { typ = 0; A = a.in[8]; abase = 0;      B = a.in[2]; Out = (ushort_t*)(ws + OFF_WQT); N = 256; mb = r >> 2; nb = r & 3; }
        else if (r < 36) { typ = 0; int rr = r - 16; A = a.in[8]; abase = 65536;  B = a.in[4]; Out = (ushort_t*)(ws + OFF_WKT); N = 320; mb = rr / 5; nb = rr % 5; }
        else if (r < 56) { typ = 0; int rr = r - 36; A = a.in[8]; abase = 131072; B = a.in[6]; Out = (ushort_t*)(ws + OFF_WVT); N = 320; mb = rr / 5; nb = rr % 5; }
        else             { typ = 1; int rr = r - 56; A = a.in[12]; abase = 0; B = a.in[10]; Out = (ushort_t*)(ws + OFF_WOT); N = 256; mb = rr >> 2; nb = rr & 3; }
        int m0 = mb * 64 + wv * 16, n0 = nb * 64;
        if (typ == 0) {
            if (fl) fuse_qkv_tile<false>(A, abase, B, Out, N, m0, n0, col, quad);
            else    fuse_qkv_tile<true >(A, abase, B, Out, N, m0, n0, col, quad);
        } else {
            if (fl) fuse_o_tile<false>(A, B, Out, m0, n0, col, quad);
            else    fuse_o_tile<true >(A, B, Out, m0, n0, col, quad);
        }
    } else {
        int m = bid - 88;
        if (fl) bias_body<false>(a, ws, m, tid);
        else    bias_body<true >(a, ws, m, tid);
    }
}

// ---------------------------------------------------------------------------
// K2: Q/K/V projections, 768 blocks x 4 waves. The 64 weight rows shared by
// all 4 waves of a block are staged once into LDS (padded stride to break
// the 512B-stride bank pattern) instead of being read 4x from global.
// Bit-identical math: same bf16 values, same MFMA order.
// ---------------------------------------------------------------------------
#define WPAD 8   // +8 bf16 = +16B row pad: bank stride 164 dwords == 4 mod 32

template <bool F32, int KK>
__device__ __forceinline__ void proj_body_lds(const void* X, const ushort_t* Wlds,
                                              const float* bias, ushort_t* Z,
                                              int m0, int n0, int col, int quad) {
    f32x4_t acc[4];
#pragma unroll
    for (int t = 0; t < 4; ++t) acc[t] = (f32x4_t){0.f, 0.f, 0.f, 0.f};
    size_t aoff = (size_t)(m0 + col) * KK + quad * 8;
    const ushort_t* Wrow = Wlds + (size_t)col * (KK + WPAD) + quad * 8;
#pragma unroll
    for (int kc = 0; kc < KK; kc += 32) {
        bf16x8_t af = ld8<F32>(X, aoff + kc);
#pragma unroll
        for (int t = 0; t < 4; ++t) {
            bf16x8_t bf = *(const bf16x8_t*)(Wrow + (size_t)t * 16 * (KK + WPAD) + kc);
            acc[t] = __builtin_amdgcn_mfma_f32_16x16x32_bf16(af, bf, acc[t], 0, 0, 0);
        }
    }
#pragma unroll
    for (int t = 0; t < 4; ++t)
#pragma unroll
        for (int rr = 0; rr < 4; ++rr) {
            int n = n0 + t * 16 + col;
            Z[(size_t)(m0 + quad * 4 + rr) * 256 + n] =
                f_to_bf16_bits(acc[t][rr] + bias[n]);
        }
}

template <bool F32, int KK>
__device__ __forceinline__ void qkv_seg(const void* X, const ushort_t* WT,
                                        const float* bias, ushort_t* Z,
                                        ushort_t* wlds, int uu,
                                        int tid, int wv, int col, int quad) {
    int m0 = (uu >> 2) * 64 + wv * 16, n0 = (uu & 3) * 64;
    // cooperative stage: 64 rows (n0..n0+63) x KK bf16 -> LDS (padded rows)
    const int CH = KK / 8;
    for (int c = tid; c < 64 * CH; c += 256) {
        int r = c / CH, cc = c - r * CH;
        *(bf16x8_t*)(wlds + (size_t)r * (KK + WPAD) + cc * 8) =
            *(const bf16x8_t*)(WT + (size_t)(n0 + r) * KK + cc * 8);
    }
    __syncthreads();
    proj_body_lds<F32, KK>(X, wlds, bias, Z, m0, n0, col, quad);
}

__global__ __launch_bounds__(256) void k_qkv(KArgs a) {
    __shared__ ushort_t wlds[64 * (320 + WPAD)];
    float* ws = a.ws;
    const int tid = threadIdx.x, u = blockIdx.x;
    const int lane = tid & 63, wv = tid >> 6;
    const int col = lane & 15, quad = lane >> 4;
    const int fl = *(const int*)(ws + OFF_FLAG);
    const float* beff = ws + OFF_BEFF;

    if (u < 256) {
        const ushort_t* WT = (const ushort_t*)(ws + OFF_WQT);
        ushort_t* Z = (ushort_t*)(ws + OFF_Q2B);
        if (fl) qkv_seg<false, 256>(a.in[0], WT, beff, Z, wlds, u, tid, wv, col, quad);
        else    qkv_seg<true , 256>(a.in[0], WT, beff, Z, wlds, u, tid, wv, col, quad);
    } else if (u < 512) {
        int uu = u - 256;
        const ushort_t* WT = (const ushort_t*)(ws + OFF_WKT);
        ushort_t* Z = (ushort_t*)(ws + OFF_K2B);
        if (fl) qkv_seg<false, 320>(a.in[1], WT, beff + 256, Z, wlds, uu, tid, wv, col, quad);
        else    qkv_seg<true , 320>(a.in[1], WT, beff + 256, Z, wlds, uu, tid, wv, col, quad);
    } else {
        int uu = u - 512;
        const ushort_t* WT = (const ushort_t*)(ws + OFF_WVT);
        ushort_t* Z = (ushort_t*)(ws + OFF_V2B);
        if (fl) qkv_seg<false, 320>(a.in[1], WT, beff + 512, Z, wlds, uu, tid, wv, col, quad);
        else    qkv_seg<true , 320>(a.in[1], WT, beff + 512, Z, wlds, uu, tid, wv, col, quad);
    }
}

// ---------------------------------------------------------------------------
// K3: attention + O-projection + residual + LayerNorm, fused. The dynamic
// K-loop is explicitly software-pipelined — iteration i+1's K/V loads are
// issued before iteration i's compute (branch is wave-uniform). Compute
// order unchanged -> bit-identical.
// ---------------------------------------------------------------------------
#define CTXP 264   // padded row length (+8 bf16 = +16B) -> 2-way banks, free

template <bool F32>
__device__ __forceinline__ void oln_part(KArgs& a, float* ws,
                                         const ushort_t ctxl[16][CTXP],
                                         float sred[8][16], float ssred[8][16],
                                         int q0, int wv, int col, int quad,
                                         int fl) {
    const ushort_t* wot  = (const ushort_t*)(ws + OFF_WOT);
    const float* beffO = ws + OFF_BEFF + 3 * 256;

    f32x4_t acc[2];
#pragma unroll
    for (int t = 0; t < 2; ++t) acc[t] = (f32x4_t){0.f, 0.f, 0.f, 0.f};
    const ushort_t* Wbase = wot + (size_t)col * 256 + quad * 8;
#pragma unroll
    for (int kc = 0; kc < 256; kc += 32) {
        bf16x8_t af = *(const bf16x8_t*)(&ctxl[col][quad * 8 + kc]);
#pragma unroll
        for (int tt = 0; tt < 2; ++tt) {
            int t = wv * 2 + tt;
            bf16x8_t bf = *(const bf16x8_t*)(Wbase + (size_t)t * 16 * 256 + kc);
            acc[tt] = __builtin_amdgcn_mfma_f32_16x16x32_bf16(af, bf, acc[tt], 0, 0, 0);
        }
    }
    float s_[4] = {0.f, 0.f, 0.f, 0.f};
    float ss_[4] = {0.f, 0.f, 0.f, 0.f};
#pragma unroll
    for (int tt = 0; tt < 2; ++tt) {
        int n = (wv * 2 + tt) * 16 + col;
        float b = beffO[n];
#pragma unroll
        for (int rr = 0; rr < 4; ++rr) {
            int m = q0 + quad * 4 + rr;
            float x = acc[tt][rr] + b + ld1f<F32>(a.in[0], (size_t)m * 256 + n);
            acc[tt][rr] = x;
            s_[rr] += x;
            ss_[rr] += x * x;
        }
    }
    // width-16 shuffle: partial row sums over this wave's 32 cols
#pragma unroll
    for (int off = 1; off < 16; off <<= 1) {
#pragma unroll
        for (int rr = 0; rr < 4; ++rr) {
            s_[rr]  += __shfl_xor(s_[rr],  off, 16);
            ss_[rr] += __shfl_xor(ss_[rr], off, 16);
        }
    }
    if (col == 0) {
#pragma unroll
        for (int rr = 0; rr < 4; ++rr) {
            sred[wv][quad * 4 + rr]  = s_[rr];
            ssred[wv][quad * 4 + rr] = ss_[rr];
        }
    }
    __syncthreads();
    float mu[4], inv[4];
#pragma unroll
    for (int rr = 0; rr < 4; ++rr) {
        int row = quad * 4 + rr;
        float ts = 0.f, tss = 0.f;
#pragma unroll
        for (int w = 0; w < 8; ++w) { ts += sred[w][row]; tss += ssred[w][row]; }
        mu[rr] = ts * (1.f / QD);
        float var = tss * (1.f / QD) - mu[rr] * mu[rr];
        inv[rr] = rsqrtf(var + LN_EPS);
    }
#pragma unroll
    for (int tt = 0; tt < 2; ++tt) {
        int n = (wv * 2 + tt) * 16 + col;
        float g = ld1f<F32>(a.in[14], n), bb = ld1f<F32>(a.in[15], n);
#pragma unroll
        for (int rr = 0; rr < 4; ++rr) {
            int m = q0 + quad * 4 + rr;
            float y = (acc[tt][rr] - mu[rr]) * inv[rr] * g + bb;
            size_t idx = (size_t)m * 256 + n;
            if (fl) ((ushort_t*)a.out)[idx] = f_to_bf16_bits(y);
            else    ((float*)a.out)[idx] = y;
        }
    }
}

__global__ __launch_bounds__(512) void k_attn_oln(KArgs a) {
    __shared__ ushort_t ctxl[16][CTXP];
    __shared__ float sred[8][16], ssred[8][16];
    float* ws = a.ws;
    const ushort_t* q2b = (const ushort_t*)(ws + OFF_Q2B);
    const ushort_t* k2b = (const ushort_t*)(ws + OFF_K2B);
    const ushort_t* v2b = (const ushort_t*)(ws + OFF_V2B);
    const ushort_t* ctxb = (const ushort_t*)(ws + OFF_CTXB);
    const int* qb  = (const int*)a.in[16];
    const int* kst = (const int*)(ws + OFF_KST);
    const int* ken = (const int*)(ws + OFF_KEN);

    const int tid = threadIdx.x;
    const int lane = tid & 63, wv = tid >> 6;     // wv = head 0..7
    const int col = lane & 15, quad = lane >> 4;
    const int fl = *(const int*)(ws + OFF_FLAG);
    const int qt = blockIdx.x;
    const int q0 = qt * 16;
    const int h  = wv;

    // seed ctx tile from legacy ctxb region (preserves stale-col semantics);
    // one bf16x8 per thread: 512 * 8 = 16 * 256
    {
        int m = tid >> 5, nblk = (tid & 31) * 8;
        *(bf16x8_t*)(&ctxl[m][nblk]) =
            *(const bf16x8_t*)(ctxb + (size_t)(q0 + m) * 256 + nblk);
    }
    __syncthreads();

    // ------------------------- attention phase ---------------------------
    {
        int qq = q0 + col;
        int bq_ = qb[qq];
        int j0q = kst[bq_], j1q = ken[bq_];
        int jlo = j0q, jhi = j1q;
#pragma unroll
        for (int off = 1; off < 16; off <<= 1) {
            jlo = min(jlo, __shfl_xor(jlo, off, 64));
            jhi = max(jhi, __shfl_xor(jhi, off, 64));
        }

        bf16x8_t qf = *(const bf16x8_t*)(q2b + (size_t)qq * HID + h * DH + quad * 8);

        f32x4_t accO  = {0.f, 0.f, 0.f, 0.f};
        f32x4_t accO2 = {0.f, 0.f, 0.f, 0.f};
        float l_st = 0.f;   // per-lane partial: sum over this lane's keys, query=col

#define ATT_LOAD(KT, KFA, KFB, VRA, VRB)                                          \
        {                                                                         \
            int ktB_ = (KT) + 16;                                                 \
            int krA_ = (KT) + col;  if (krA_ > NK - 1) krA_ = NK - 1;             \
            int krB_ = ktB_ + col;  if (krB_ > NK - 1) krB_ = NK - 1;             \
            KFA = *(const bf16x8_t*)(k2b + (size_t)krA_ * HID + h * DH + quad * 8); \
            KFB = *(const bf16x8_t*)(k2b + (size_t)krB_ * HID + h * DH + quad * 8); \
            _Pragma("unroll")                                                     \
            for (int j = 0; j < 4; ++j) {                                         \
                int vrA_ = (KT) + quad * 4 + j;  if (vrA_ > NK - 1) vrA_ = NK - 1;  \
                int vrB_ = ktB_ + quad * 4 + j;  if (vrB_ > NK - 1) vrB_ = NK - 1;  \
                VRA[j] = v2b[(size_t)vrA_ * HID + h * DH + col];                  \
                VRB[j] = v2b[(size_t)vrB_ * HID + h * DH + col];                  \
            }                                                                     \
        }

        if (jlo < jhi) {
            bf16x8_t kfA, kfB, kfA2, kfB2;
            ushort_t vrA[4], vrB[4], vrA2[4], vrB2[4];
            ATT_LOAD(jlo, kfA, kfB, vrA, vrB);
            for (int kt = jlo; ; ) {
                int ktn = kt + 32;
                bool more = ktn < jhi;     // wave-uniform (jlo/jhi wave-reduced)
                if (more) ATT_LOAD(ktn, kfA2, kfB2, vrA2, vrB2);

                int ktB = kt + 16;
                // S tile: row (quad*4+r) = key, col (lane&15) = query
                f32x4_t SA = __builtin_amdgcn_mfma_f32_16x16x32_bf16(
                    kfA, qf, (f32x4_t){0.f, 0.f, 0.f, 0.f}, 0, 0, 0);
                f32x4_t SB = __builtin_amdgcn_mfma_f32_16x16x32_bf16(
                    kfB, qf, (f32x4_t){0.f, 0.f, 0.f, 0.f}, 0, 0, 0);

                bf16x4_t pbA, vbA, pbB, vbB;
#pragma unroll
                for (int r = 0; r < 4; ++r) {
                    int kkA = kt + quad * 4 + r;
                    bool okA = (kkA >= j0q) && (kkA < j1q);
                    float pA = okA ? __expf(SA[r] * ATT_SCALE) : 0.f;
                    l_st += pA;
                    pbA[r] = (short)f_to_bf16_bits(pA);
                    vbA[r] = (short)vrA[r];
                    int kkB = ktB + quad * 4 + r;
                    bool okB = (kkB >= j0q) && (kkB < j1q);
                    float pB = okB ? __expf(SB[r] * ATT_SCALE) : 0.f;
                    l_st += pB;
                    pbB[r] = (short)f_to_bf16_bits(pB);
                    vbB[r] = (short)vrB[r];
                }
                accO  = __builtin_amdgcn_mfma_f32_16x16x16bf16_1k(pbA, vbA, accO,  0, 0, 0);
                accO2 = __builtin_amdgcn_mfma_f32_16x16x16bf16_1k(pbB, vbB, accO2, 0, 0, 0);

                if (!more) break;
                kfA = kfA2; kfB = kfB2;
#pragma unroll
                for (int j = 0; j < 4; ++j) { vrA[j] = vrA2[j]; vrB[j] = vrB2[j]; }
                kt = ktn;
            }
        }
#undef ATT_LOAD

#pragma unroll
        for (int r = 0; r < 4; ++r) accO[r] += accO2[r];

        // total l per query=col: reduce across the 4 quads
        l_st += __shfl_xor(l_st, 16, 64);
        l_st += __shfl_xor(l_st, 32, 64);

#pragma unroll
        for (int r = 0; r < 4; ++r) {
            int qrow_local = quad * 4 + r;               // accO row = query index
            float lq = __shfl(l_st, qrow_local, 64);     // lane qrow_local has col==qrow_local
            float o = (lq > 0.f) ? accO[r] / lq : 0.f;
            ctxl[qrow_local][h * DH + col] = f_to_bf16_bits(o);
        }
    }
    __syncthreads();

    // ---------------- O-projection + residual + LayerNorm -----------------
    if (fl) oln_part<false>(a, ws, ctxl, sred, ssred, q0, wv, col, quad, fl);
    else    oln_part<true >(a, ws, ctxl, sred, ssred, q0, wv, col, quad, fl);
}

extern "C" void kernel_launch(void* const* d_in, const int* in_sizes, int n_in,
                              void* d_out, int out_size, void* d_ws, size_t ws_size,
                              hipStream_t stream) {
    KArgs a;
    for (int i = 0; i < 18; ++i) a.in[i] = d_in[i];
    a.ws = (float*)d_ws;
    a.out = d_out;

    k_fuse<<<92, 256, 0, stream>>>(a);
    k_qkv<<<768, 256, 0, stream>>>(a);
    k_attn_oln<<<256, 512, 0, stream>>>(a);
}